// Round 1
// baseline (3582.216 us; speedup 1.0000x reference)
//
#include <hip/hip_runtime.h>

#define BB 32
#define TT 2048
#define SS 32
#define DD 80
#define HH 256
#define VV 1024
#define EBD 64

// ---------------------------------------------------------------------------
// Kernel A: polynomial rolling hashes + table gathers + conditioned long keys
// raw[b,t,8] = [tab0[k0](2), tab1[k1](2), tab2[lk2](2), tab3[lk3](2)]
// ---------------------------------------------------------------------------
__global__ __launch_bounds__(256) void k_hash(const int* __restrict__ tok,
                                              const float* __restrict__ t0,
                                              const float* __restrict__ t1,
                                              const float* __restrict__ t2,
                                              const float* __restrict__ t3,
                                              const float* __restrict__ cond_w,
                                              float* __restrict__ raw) {
    int idx = blockIdx.x * 256 + threadIdx.x;
    if (idx >= BB * TT) return;
    int b = idx / TT, t = idx % TT;
    const int* tr = tok + b * TT;

    unsigned long long tv[8];
#pragma unroll
    for (int i = 0; i < 8; i++) {
        int ts = t - 1 - i;
        tv[i] = (ts >= 0) ? (unsigned long long)(unsigned)tr[ts] : 0ull;
    }
    const unsigned long long P[8] = {2654435761ull, 2246822519ull, 3266489917ull,
                                     2028178513ull, 1220703125ull, 1610612741ull,
                                     805306457ull, 402653189ull};
    unsigned long long x = 0ull;
    x ^= tv[0] * P[0]; unsigned long long k0 = x % 2000000ull;
    x ^= tv[1] * P[1]; unsigned long long k1 = x % 2000000ull;
    x ^= tv[2] * P[2]; x ^= tv[3] * P[3]; unsigned long long k2 = x % 2000000ull;
    x ^= tv[4] * P[4]; x ^= tv[5] * P[5];
    x ^= tv[6] * P[6]; x ^= tv[7] * P[7]; unsigned long long k3 = x % 2000000ull;

    float f0 = t0[k0 * 2], f1 = t0[k0 * 2 + 1];
    float f2 = t1[k1 * 2], f3 = t1[k1 * 2 + 1];

    unsigned long long ck = 0ull;
#pragma unroll
    for (int j = 0; j < 8; j++) {
        float lg = f0 * cond_w[j * 4 + 0] + f1 * cond_w[j * 4 + 1] +
                   f2 * cond_w[j * 4 + 2] + f3 * cond_w[j * 4 + 3];
        if (lg > 0.f) ck ^= P[j];
    }
    unsigned long long lk2 = (k2 ^ ck) % 2000000ull;
    unsigned long long lk3 = (k3 ^ ck) % 2000000ull;

    float* o = raw + (size_t)idx * 8;
    o[0] = f0; o[1] = f1; o[2] = f2; o[3] = f3;
    o[4] = t2[lk2 * 2]; o[5] = t2[lk2 * 2 + 1];
    o[6] = t3[lk3 * 2]; o[7] = t3[lk3 * 2 + 1];
}

// ---------------------------------------------------------------------------
// Kernel B: causal depthwise conv (K=8) + silu over raw hash feats,
// assemble h[b,t,80] = [byte_emb(64), hash_feat(8), match_feat(8)]
// ---------------------------------------------------------------------------
__global__ __launch_bounds__(256) void k_feat(const int* __restrict__ tok,
                                              const float* __restrict__ be,
                                              const float* __restrict__ raw,
                                              const float* __restrict__ conv_w,
                                              const float* __restrict__ conv_b,
                                              float* __restrict__ hf) {
    int idx = blockIdx.x * 256 + threadIdx.x;
    if (idx >= BB * TT) return;
    int b = idx / TT, t = idx % TT;
    const int* tr = tok + b * TT;
    float* o = hf + (size_t)idx * DD;

    // byte embedding
    int tk = tr[t];
    const float* ber = be + (size_t)tk * EBD;
#pragma unroll 8
    for (int d = 0; d < EBD; d++) o[d] = ber[d];

    // conv: out[c,t] = sum_k w[c,k] * raw[t-7+k, c]
#pragma unroll
    for (int c = 0; c < 8; c++) {
        float acc = conv_b[c];
#pragma unroll
        for (int k = 0; k < 8; k++) {
            int ts = t - 7 + k;
            if (ts >= 0) acc += conv_w[c * 8 + k] * raw[((size_t)(b * TT + ts)) * 8 + c];
        }
        o[64 + c] = acc / (1.f + expf(-acc));  // silu
    }

    // match features k=1..8
#pragma unroll
    for (int k = 1; k <= 8; k++) {
        float m = (t >= k && tr[t] == tr[t - k]) ? 1.f : 0.f;
        o[71 + k] = m;
    }
}

// ---------------------------------------------------------------------------
// Kernel C: gates. a[b,s,t] = sigmoid(h.gw[s]+gb[s]); drive=(1-a)*(h.iw[s]+ib[s])
// Output layout [B*S, T] for the sequential scan.
// ---------------------------------------------------------------------------
__global__ __launch_bounds__(256) void k_gates(const float* __restrict__ hf,
                                               const float* __restrict__ gw,
                                               const float* __restrict__ gb,
                                               const float* __restrict__ iw,
                                               const float* __restrict__ ib,
                                               float* __restrict__ Ag,
                                               float* __restrict__ Dr) {
    __shared__ float xs[64][DD];
    int blk = blockIdx.x;
    int b = blk >> 5;                 // T/64 = 32 tiles per batch
    int t0 = (blk & 31) << 6;
    const float* src = hf + ((size_t)(b * TT + t0)) * DD;
    for (int i = threadIdx.x; i < 64 * DD; i += 256) xs[i / DD][i % DD] = src[i];
    __syncthreads();

    for (int p = threadIdx.x; p < 64 * SS; p += 256) {
        int s = p & 31, tt = p >> 5;
        float ga = gb[s], ia = ib[s];
        for (int d = 0; d < DD; d++) {
            float xv = xs[tt][d];
            ga += xv * gw[s * DD + d];
            ia += xv * iw[s * DD + d];
        }
        float g = 1.f / (1.f + expf(-ga));
        float drv = (1.f - g) * ia;
        size_t oo = ((size_t)(b * SS + s)) * TT + t0 + tt;
        Ag[oo] = g;
        Dr[oo] = drv;
    }
}

// ---------------------------------------------------------------------------
// Kernel D: sequential chunked scan, replicating reference clamp semantics.
// One thread per (b,s). states written [B,T,S].
// ---------------------------------------------------------------------------
__global__ __launch_bounds__(256) void k_scan(const float* __restrict__ Ag,
                                              const float* __restrict__ Dr,
                                              float* __restrict__ st) {
    int tid = blockIdx.x * 256 + threadIdx.x;
    if (tid >= BB * SS) return;
    int b = tid / SS, s = tid % SS;
    const float* ar = Ag + (size_t)tid * TT;
    const float* dr = Dr + (size_t)tid * TT;

    float h0 = 0.f;
    for (int c = 0; c < TT / 32; c++) {
        float lacc = 0.f, wacc = 0.f, out = 0.f;
#pragma unroll 8
        for (int k = 0; k < 32; k++) {
            float a = ar[c * 32 + k];
            float dv = dr[c * 32 + k];
            lacc += logf(fmaxf(a, 1e-6f));
            float ca = expf(lacc);
            wacc += dv / fmaxf(ca, 1e-8f);
            out = ca * (h0 + wacc);
            st[((size_t)(b * TT + c * 32 + k)) * SS + s] = out;
        }
        h0 = out;
    }
}

// ---------------------------------------------------------------------------
// Kernel E: y = states @ outpr_w^T + ob ; h1 = LN(hf + y)
// ---------------------------------------------------------------------------
__global__ __launch_bounds__(256) void k_post(const float* __restrict__ st,
                                              const float* __restrict__ hf,
                                              const float* __restrict__ ow,
                                              const float* __restrict__ ob,
                                              const float* __restrict__ lnw,
                                              const float* __restrict__ lnb,
                                              float* __restrict__ h1) {
    int idx = blockIdx.x * 256 + threadIdx.x;
    if (idx >= BB * TT) return;
    const float* sp = st + (size_t)idx * SS;
    float sv[SS];
#pragma unroll
    for (int i = 0; i < SS; i++) sv[i] = sp[i];
    const float* x = hf + (size_t)idx * DD;

    float s1 = 0.f, s2 = 0.f;
    for (int d = 0; d < DD; d++) {
        float acc = ob[d];
#pragma unroll
        for (int i = 0; i < SS; i++) acc += sv[i] * ow[d * SS + i];
        float v = acc + x[d];
        s1 += v; s2 += v * v;
    }
    float m = s1 * (1.f / DD);
    float var = s2 * (1.f / DD) - m * m;
    float rs = rsqrtf(var + 1e-5f);
    for (int d = 0; d < DD; d++) {
        float acc = ob[d];
#pragma unroll
        for (int i = 0; i < SS; i++) acc += sv[i] * ow[d * SS + i];
        float v = acc + x[d];
        h1[(size_t)idx * DD + d] = (v - m) * rs * lnw[d] + lnb[d];
    }
}

// ---------------------------------------------------------------------------
// Kernel F: h2 = silu(h1 @ inp_w^T + inp_b), 80 -> 256
// ---------------------------------------------------------------------------
__global__ __launch_bounds__(256) void k_mlp1(const float* __restrict__ h1,
                                              const float* __restrict__ w,
                                              const float* __restrict__ bias,
                                              float* __restrict__ h2) {
    __shared__ float xs[64][DD];
    int blk = blockIdx.x;
    int b = blk >> 5;
    int t0 = (blk & 31) << 6;
    const float* src = h1 + ((size_t)(b * TT + t0)) * DD;
    for (int i = threadIdx.x; i < 64 * DD; i += 256) xs[i / DD][i % DD] = src[i];
    __syncthreads();

    int j = threadIdx.x;
    float bj = bias[j];
    for (int tt0 = 0; tt0 < 64; tt0 += 16) {
        float acc[16];
#pragma unroll
        for (int r = 0; r < 16; r++) acc[r] = bj;
        for (int d = 0; d < DD; d++) {
            float wv = w[j * DD + d];
#pragma unroll
            for (int r = 0; r < 16; r++) acc[r] += xs[tt0 + r][d] * wv;
        }
#pragma unroll
        for (int r = 0; r < 16; r++) {
            float v = acc[r];
            h2[((size_t)(b * TT + t0 + tt0 + r)) * HH + j] = v / (1.f + expf(-v));
        }
    }
}

// ---------------------------------------------------------------------------
// Kernel G: gated MLP (256x256 x3) + residual + LN
// block = 256 threads, 16 rows per block
// ---------------------------------------------------------------------------
__global__ __launch_bounds__(256) void k_gmlp(const float* __restrict__ h2,
                                              const float* __restrict__ w1,
                                              const float* __restrict__ w2,
                                              const float* __restrict__ wp,
                                              const float* __restrict__ lnw,
                                              const float* __restrict__ lnb,
                                              float* __restrict__ h3) {
    __shared__ float X[16][HH];
    __shared__ float U[16][HH];
    __shared__ float mred[16], vred[16];
    int row0 = blockIdx.x * 16;
    for (int i = threadIdx.x; i < 16 * HH; i += 256)
        X[i >> 8][i & 255] = h2[(size_t)row0 * HH + i];
    __syncthreads();

    int j = threadIdx.x;
    float a1[16], a2[16];
#pragma unroll
    for (int r = 0; r < 16; r++) { a1[r] = 0.f; a2[r] = 0.f; }
    for (int d = 0; d < HH; d++) {
        float wv1 = w1[j * HH + d], wv2 = w2[j * HH + d];
#pragma unroll
        for (int r = 0; r < 16; r++) {
            float xv = X[r][d];
            a1[r] += xv * wv1;
            a2[r] += xv * wv2;
        }
    }
#pragma unroll
    for (int r = 0; r < 16; r++)
        U[r][j] = (a1[r] / (1.f + expf(-a1[r]))) * a2[r];
    __syncthreads();

    float hh[16];
#pragma unroll
    for (int r = 0; r < 16; r++) hh[r] = 0.f;
    for (int d = 0; d < HH; d++) {
        float wv = wp[j * HH + d];
#pragma unroll
        for (int r = 0; r < 16; r++) hh[r] += U[r][d] * wv;
    }
    __syncthreads();  // done reading U
#pragma unroll
    for (int r = 0; r < 16; r++) U[r][j] = hh[r] + X[r][j];  // V = hh + residual
    __syncthreads();

    if (j < 16) {
        float s1 = 0.f, s2 = 0.f;
        for (int d = 0; d < HH; d++) { float v = U[j][d]; s1 += v; s2 += v * v; }
        float m = s1 * (1.f / HH);
        mred[j] = m;
        vred[j] = rsqrtf(s2 * (1.f / HH) - m * m + 1e-5f);
    }
    __syncthreads();

    float lw = lnw[j], lb = lnb[j];
#pragma unroll
    for (int r = 0; r < 16; r++)
        h3[((size_t)(row0 + r)) * HH + j] = (U[r][j] - mred[r]) * vred[r] * lw + lb;
}

// ---------------------------------------------------------------------------
// Kernel H: out = h3 @ out_w^T + out_b, 256 -> 1024
// ---------------------------------------------------------------------------
__global__ __launch_bounds__(256) void k_out(const float* __restrict__ h3,
                                             const float* __restrict__ w,
                                             const float* __restrict__ bias,
                                             float* __restrict__ out) {
    __shared__ float X[16][HH];
    int row0 = blockIdx.x * 16;
    for (int i = threadIdx.x; i < 16 * HH; i += 256)
        X[i >> 8][i & 255] = h3[(size_t)row0 * HH + i];
    __syncthreads();

    int j = threadIdx.x;
    float acc[4][16];
#pragma unroll
    for (int vb = 0; vb < 4; vb++)
#pragma unroll
        for (int r = 0; r < 16; r++) acc[vb][r] = 0.f;

    for (int d = 0; d < HH; d++) {
        float wv[4];
#pragma unroll
        for (int vb = 0; vb < 4; vb++) wv[vb] = w[((size_t)(vb * 256 + j)) * HH + d];
#pragma unroll
        for (int r = 0; r < 16; r++) {
            float xv = X[r][d];
#pragma unroll
            for (int vb = 0; vb < 4; vb++) acc[vb][r] += xv * wv[vb];
        }
    }
#pragma unroll
    for (int vb = 0; vb < 4; vb++) {
        float bv = bias[vb * 256 + j];
#pragma unroll
        for (int r = 0; r < 16; r++)
            out[((size_t)(row0 + r)) * VV + vb * 256 + j] = acc[vb][r] + bv;
    }
}

// ---------------------------------------------------------------------------
extern "C" void kernel_launch(void* const* d_in, const int* in_sizes, int n_in,
                              void* d_out, int out_size, void* d_ws, size_t ws_size,
                              hipStream_t stream) {
    const int* chars        = (const int*)d_in[0];
    const float* byte_embed = (const float*)d_in[1];
    const float* table0     = (const float*)d_in[2];
    const float* table1     = (const float*)d_in[3];
    const float* table2     = (const float*)d_in[4];
    const float* table3     = (const float*)d_in[5];
    const float* cond_w     = (const float*)d_in[6];
    const float* conv_w     = (const float*)d_in[7];
    const float* conv_b     = (const float*)d_in[8];
    const float* gate_w     = (const float*)d_in[9];
    const float* gate_b     = (const float*)d_in[10];
    const float* inpr_w     = (const float*)d_in[11];
    const float* inpr_b     = (const float*)d_in[12];
    const float* outpr_w    = (const float*)d_in[13];
    const float* outpr_b    = (const float*)d_in[14];
    const float* scan_ln_w  = (const float*)d_in[15];
    const float* scan_ln_b  = (const float*)d_in[16];
    const float* inp_w      = (const float*)d_in[17];
    const float* inp_b      = (const float*)d_in[18];
    const float* r_w1       = (const float*)d_in[19];
    const float* r_w2       = (const float*)d_in[20];
    const float* r_proj     = (const float*)d_in[21];
    const float* r_ln_w     = (const float*)d_in[22];
    const float* r_ln_b     = (const float*)d_in[23];
    const float* out_w      = (const float*)d_in[24];
    const float* out_b      = (const float*)d_in[25];

    // workspace layout (needs ~66 MB of d_ws; h2 lives in d_out as scratch)
    char* ws = (char*)d_ws;
    float* raw = (float*)(ws + 0);           //  2 MB  [B,T,8]
    float* hf  = (float*)(ws + 2097152);     // 20 MB  [B,T,80]
    float* Ag  = (float*)(ws + 23068672);    //  8 MB  [B*S,T]
    float* Dr  = (float*)(ws + 31457280);    //  8 MB  [B*S,T]
    float* st  = (float*)(ws + 39845888);    //  8 MB  [B,T,S]
    float* h1  = (float*)(ws + 48234496);    // 20 MB  [B,T,80]  (ends 69,206,016)
    float* h2  = (float*)d_out;              // 64 MB scratch in d_out [B,T,256]
    float* h3  = (float*)(ws + 0);           // 64 MB, overlaps raw..h1 (all dead)
    float* out = (float*)d_out;

    k_hash <<<256, 256, 0, stream>>>(chars, table0, table1, table2, table3, cond_w, raw);
    k_feat <<<256, 256, 0, stream>>>(chars, byte_embed, raw, conv_w, conv_b, hf);
    k_gates<<<1024, 256, 0, stream>>>(hf, gate_w, gate_b, inpr_w, inpr_b, Ag, Dr);
    k_scan <<<4, 256, 0, stream>>>(Ag, Dr, st);
    k_post <<<256, 256, 0, stream>>>(st, hf, outpr_w, outpr_b, scan_ln_w, scan_ln_b, h1);
    k_mlp1 <<<1024, 256, 0, stream>>>(h1, inp_w, inp_b, h2);
    k_gmlp <<<4096, 256, 0, stream>>>(h2, r_w1, r_w2, r_proj, r_ln_w, r_ln_b, h3);
    k_out  <<<4096, 256, 0, stream>>>(h3, out_w, out_b, out);
}

// Round 2
// 789.456 us; speedup vs baseline: 4.5376x; 4.5376x over previous
//
#include <hip/hip_runtime.h>

#define BB 32
#define TT 2048
#define SS 32
#define DD 80
#define HH 256
#define VV 1024
#define EBD 64

typedef unsigned short u16;
typedef __attribute__((ext_vector_type(8))) __bf16 bf16x8;
typedef __attribute__((ext_vector_type(4))) float f32x4;

#define MFMA(a, b, c) __builtin_amdgcn_mfma_f32_16x16x32_bf16(a, b, c, 0, 0, 0)

__device__ inline u16 f2bu(float f) {
    unsigned u = __float_as_uint(f);
    return (u16)((u + 0x7FFFu + ((u >> 16) & 1u)) >> 16);
}
__device__ inline __bf16 f2b(float f) {
    u16 r = f2bu(f);
    return __builtin_bit_cast(__bf16, r);
}
__device__ inline float b2f(u16 h) { return __uint_as_float(((unsigned)h) << 16); }

// A/B fragment (16 rows x 32 k) from bf16 row-major [.][256]; row includes lane&15
__device__ inline bf16x8 ldfrag(const u16* base, int row, int k0, int lane) {
    return *(const bf16x8*)(base + (size_t)row * 256 + k0 + ((lane >> 4) << 3));
}
// Same fragment from f32 row-major [.][256], converted in-register
__device__ inline bf16x8 ldfragf(const float* base, int row, int k0, int lane) {
    const float* p = base + (size_t)row * 256 + k0 + ((lane >> 4) << 3);
    f32x4 w0 = *(const f32x4*)p;
    f32x4 w1 = *(const f32x4*)(p + 4);
    bf16x8 b;
    b[0] = f2b(w0[0]); b[1] = f2b(w0[1]); b[2] = f2b(w0[2]); b[3] = f2b(w0[3]);
    b[4] = f2b(w1[0]); b[5] = f2b(w1[1]); b[6] = f2b(w1[2]); b[7] = f2b(w1[3]);
    return b;
}

// ---------------------------------------------------------------------------
// Kernel A: polynomial rolling hashes + table gathers + conditioned long keys
// ---------------------------------------------------------------------------
__global__ __launch_bounds__(256) void k_hash(const int* __restrict__ tok,
                                              const float* __restrict__ t0,
                                              const float* __restrict__ t1,
                                              const float* __restrict__ t2,
                                              const float* __restrict__ t3,
                                              const float* __restrict__ cond_w,
                                              float* __restrict__ raw) {
    int idx = blockIdx.x * 256 + threadIdx.x;
    if (idx >= BB * TT) return;
    int b = idx / TT, t = idx % TT;
    const int* tr = tok + b * TT;

    unsigned long long tv[8];
#pragma unroll
    for (int i = 0; i < 8; i++) {
        int ts = t - 1 - i;
        tv[i] = (ts >= 0) ? (unsigned long long)(unsigned)tr[ts] : 0ull;
    }
    const unsigned long long P[8] = {2654435761ull, 2246822519ull, 3266489917ull,
                                     2028178513ull, 1220703125ull, 1610612741ull,
                                     805306457ull, 402653189ull};
    unsigned long long x = 0ull;
    x ^= tv[0] * P[0]; unsigned long long k0 = x % 2000000ull;
    x ^= tv[1] * P[1]; unsigned long long k1 = x % 2000000ull;
    x ^= tv[2] * P[2]; x ^= tv[3] * P[3]; unsigned long long k2 = x % 2000000ull;
    x ^= tv[4] * P[4]; x ^= tv[5] * P[5];
    x ^= tv[6] * P[6]; x ^= tv[7] * P[7]; unsigned long long k3 = x % 2000000ull;

    float f0 = t0[k0 * 2], f1 = t0[k0 * 2 + 1];
    float f2 = t1[k1 * 2], f3 = t1[k1 * 2 + 1];

    unsigned long long ck = 0ull;
#pragma unroll
    for (int j = 0; j < 8; j++) {
        float lg = f0 * cond_w[j * 4 + 0] + f1 * cond_w[j * 4 + 1] +
                   f2 * cond_w[j * 4 + 2] + f3 * cond_w[j * 4 + 3];
        if (lg > 0.f) ck ^= P[j];
    }
    unsigned long long lk2 = (k2 ^ ck) % 2000000ull;
    unsigned long long lk3 = (k3 ^ ck) % 2000000ull;

    float* o = raw + (size_t)idx * 8;
    o[0] = f0; o[1] = f1; o[2] = f2; o[3] = f3;
    o[4] = t2[lk2 * 2]; o[5] = t2[lk2 * 2 + 1];
    o[6] = t3[lk3 * 2]; o[7] = t3[lk3 * 2 + 1];
}

// ---------------------------------------------------------------------------
// Kernel B: causal depthwise conv + silu, assemble h[b,t,80]
// ---------------------------------------------------------------------------
__global__ __launch_bounds__(256) void k_feat(const int* __restrict__ tok,
                                              const float* __restrict__ be,
                                              const float* __restrict__ raw,
                                              const float* __restrict__ conv_w,
                                              const float* __restrict__ conv_b,
                                              float* __restrict__ hf) {
    int idx = blockIdx.x * 256 + threadIdx.x;
    if (idx >= BB * TT) return;
    int b = idx / TT, t = idx % TT;
    const int* tr = tok + b * TT;
    float* o = hf + (size_t)idx * DD;

    int tk = tr[t];
    const float* ber = be + (size_t)tk * EBD;
#pragma unroll 8
    for (int d = 0; d < EBD; d++) o[d] = ber[d];

#pragma unroll
    for (int c = 0; c < 8; c++) {
        float acc = conv_b[c];
#pragma unroll
        for (int k = 0; k < 8; k++) {
            int ts = t - 7 + k;
            if (ts >= 0) acc += conv_w[c * 8 + k] * raw[((size_t)(b * TT + ts)) * 8 + c];
        }
        o[64 + c] = acc / (1.f + expf(-acc));
    }

#pragma unroll
    for (int k = 1; k <= 8; k++) {
        float m = (t >= k && tr[t] == tr[t - k]) ? 1.f : 0.f;
        o[71 + k] = m;
    }
}

// ---------------------------------------------------------------------------
// Kernel C: scan gates
// ---------------------------------------------------------------------------
__global__ __launch_bounds__(256) void k_gates(const float* __restrict__ hf,
                                               const float* __restrict__ gw,
                                               const float* __restrict__ gb,
                                               const float* __restrict__ iw,
                                               const float* __restrict__ ib,
                                               float* __restrict__ Ag,
                                               float* __restrict__ Dr) {
    __shared__ float xs[64][DD];
    int blk = blockIdx.x;
    int b = blk >> 5;
    int t0 = (blk & 31) << 6;
    const float* src = hf + ((size_t)(b * TT + t0)) * DD;
    for (int i = threadIdx.x; i < 64 * DD; i += 256) xs[i / DD][i % DD] = src[i];
    __syncthreads();

    for (int p = threadIdx.x; p < 64 * SS; p += 256) {
        int s = p & 31, tt = p >> 5;
        float ga = gb[s], ia = ib[s];
        for (int d = 0; d < DD; d++) {
            float xv = xs[tt][d];
            ga += xv * gw[s * DD + d];
            ia += xv * iw[s * DD + d];
        }
        float g = 1.f / (1.f + expf(-ga));
        float drv = (1.f - g) * ia;
        size_t oo = ((size_t)(b * SS + s)) * TT + t0 + tt;
        Ag[oo] = g;
        Dr[oo] = drv;
    }
}

// ---------------------------------------------------------------------------
// Kernel D: sequential chunked scan (reference clamp semantics)
// ---------------------------------------------------------------------------
__global__ __launch_bounds__(256) void k_scan(const float* __restrict__ Ag,
                                              const float* __restrict__ Dr,
                                              float* __restrict__ st) {
    int tid = blockIdx.x * 256 + threadIdx.x;
    if (tid >= BB * SS) return;
    int b = tid / SS, s = tid % SS;
    const float* ar = Ag + (size_t)tid * TT;
    const float* dr = Dr + (size_t)tid * TT;

    float h0 = 0.f;
    for (int c = 0; c < TT / 32; c++) {
        float lacc = 0.f, wacc = 0.f, out = 0.f;
#pragma unroll 8
        for (int k = 0; k < 32; k++) {
            float a = ar[c * 32 + k];
            float dv = dr[c * 32 + k];
            lacc += logf(fmaxf(a, 1e-6f));
            float ca = expf(lacc);
            wacc += dv / fmaxf(ca, 1e-8f);
            out = ca * (h0 + wacc);
            st[((size_t)(b * TT + c * 32 + k)) * SS + s] = out;
        }
        h0 = out;
    }
}

// ---------------------------------------------------------------------------
// Kernel E: y = states @ outpr_w^T + ob ; h1 = LN(hf + y)
// ---------------------------------------------------------------------------
__global__ __launch_bounds__(256) void k_post(const float* __restrict__ st,
                                              const float* __restrict__ hf,
                                              const float* __restrict__ ow,
                                              const float* __restrict__ ob,
                                              const float* __restrict__ lnw,
                                              const float* __restrict__ lnb,
                                              float* __restrict__ h1) {
    int idx = blockIdx.x * 256 + threadIdx.x;
    if (idx >= BB * TT) return;
    const float* sp = st + (size_t)idx * SS;
    float sv[SS];
#pragma unroll
    for (int i = 0; i < SS; i++) sv[i] = sp[i];
    const float* x = hf + (size_t)idx * DD;

    float s1 = 0.f, s2 = 0.f;
    for (int d = 0; d < DD; d++) {
        float acc = ob[d];
#pragma unroll
        for (int i = 0; i < SS; i++) acc += sv[i] * ow[d * SS + i];
        float v = acc + x[d];
        s1 += v; s2 += v * v;
    }
    float m = s1 * (1.f / DD);
    float var = s2 * (1.f / DD) - m * m;
    float rs = rsqrtf(var + 1e-5f);
    for (int d = 0; d < DD; d++) {
        float acc = ob[d];
#pragma unroll
        for (int i = 0; i < SS; i++) acc += sv[i] * ow[d * SS + i];
        float v = acc + x[d];
        h1[(size_t)idx * DD + d] = (v - m) * rs * lnw[d] + lnb[d];
    }
}

// ---------------------------------------------------------------------------
// Kernel F: h2 = silu(h1 @ inp_w^T + inp_b), 80 -> 256, bf16 out
// ---------------------------------------------------------------------------
__global__ __launch_bounds__(256) void k_mlp1(const float* __restrict__ h1,
                                              const float* __restrict__ w,
                                              const float* __restrict__ bias,
                                              u16* __restrict__ h2) {
    __shared__ float xs[64][DD];
    int blk = blockIdx.x;
    int b = blk >> 5;
    int t0 = (blk & 31) << 6;
    const float* src = h1 + ((size_t)(b * TT + t0)) * DD;
    for (int i = threadIdx.x; i < 64 * DD; i += 256) xs[i / DD][i % DD] = src[i];
    __syncthreads();

    int j = threadIdx.x;
    float bj = bias[j];
    for (int tt0 = 0; tt0 < 64; tt0 += 16) {
        float acc[16];
#pragma unroll
        for (int r = 0; r < 16; r++) acc[r] = bj;
        for (int d = 0; d < DD; d++) {
            float wv = w[j * DD + d];
#pragma unroll
            for (int r = 0; r < 16; r++) acc[r] += xs[tt0 + r][d] * wv;
        }
#pragma unroll
        for (int r = 0; r < 16; r++) {
            float v = acc[r];
            h2[((size_t)(b * TT + t0 + tt0 + r)) * HH + j] = f2bu(v / (1.f + expf(-v)));
        }
    }
}

// ---------------------------------------------------------------------------
// Kernel G1 (MFMA): U = silu(X@w1^T) * (X@w2^T), bf16 in/out, K=256
// grid (1024, 2): 64-row blocks x 128-col halves; wave computes 64x32
// ---------------------------------------------------------------------------
__global__ __launch_bounds__(256) void k_gemm_u(const u16* __restrict__ x,
                                                const float* __restrict__ w1,
                                                const float* __restrict__ w2,
                                                u16* __restrict__ U) {
    int lane = threadIdx.x & 63, wv = threadIdx.x >> 6;
    int r0 = blockIdx.x * 64;
    int c0 = blockIdx.y * 128 + wv * 32;
    f32x4 a1[4][2] = {}, a2[4][2] = {};
    for (int ks = 0; ks < 8; ks++) {
        int k0 = ks * 32;
        bf16x8 a[4];
#pragma unroll
        for (int mi = 0; mi < 4; mi++) a[mi] = ldfrag(x, r0 + mi * 16 + (lane & 15), k0, lane);
#pragma unroll
        for (int ni = 0; ni < 2; ni++) {
            bf16x8 b1 = ldfragf(w1, c0 + ni * 16 + (lane & 15), k0, lane);
            bf16x8 b2 = ldfragf(w2, c0 + ni * 16 + (lane & 15), k0, lane);
#pragma unroll
            for (int mi = 0; mi < 4; mi++) {
                a1[mi][ni] = MFMA(a[mi], b1, a1[mi][ni]);
                a2[mi][ni] = MFMA(a[mi], b2, a2[mi][ni]);
            }
        }
    }
    int g = lane >> 4, cl = lane & 15;
#pragma unroll
    for (int mi = 0; mi < 4; mi++)
#pragma unroll
        for (int ni = 0; ni < 2; ni++)
#pragma unroll
            for (int r = 0; r < 4; r++) {
                float v1 = a1[mi][ni][r], v2 = a2[mi][ni][r];
                float u = v1 / (1.f + expf(-v1)) * v2;
                U[(size_t)(r0 + mi * 16 + g * 4 + r) * 256 + c0 + ni * 16 + cl] = f2bu(u);
            }
}

// ---------------------------------------------------------------------------
// Kernel G2 (MFMA): hh = U@wp^T; V = hh + X; h3 = LN(V), bf16 out
// grid 1024 x 256thr; wave computes 64 rows x 64 cols. h3 may alias U
// (block writes only its own rows, strictly after its K-loop reads).
// ---------------------------------------------------------------------------
__global__ __launch_bounds__(256) void k_gemm_proj(const u16* __restrict__ U,
                                                   const float* __restrict__ wp,
                                                   const u16* __restrict__ x,
                                                   const float* __restrict__ lnw,
                                                   const float* __restrict__ lnb,
                                                   u16* __restrict__ h3) {
    __shared__ float redS[64][4], redQ[64][4];
    int lane = threadIdx.x & 63, wv = threadIdx.x >> 6;
    int r0 = blockIdx.x * 64;
    int c0 = wv * 64;
    f32x4 acc[4][4] = {};
    for (int ks = 0; ks < 8; ks++) {
        int k0 = ks * 32;
        bf16x8 a[4];
#pragma unroll
        for (int mi = 0; mi < 4; mi++) a[mi] = ldfrag(U, r0 + mi * 16 + (lane & 15), k0, lane);
#pragma unroll
        for (int ni = 0; ni < 4; ni++) {
            bf16x8 b = ldfragf(wp, c0 + ni * 16 + (lane & 15), k0, lane);
#pragma unroll
            for (int mi = 0; mi < 4; mi++) acc[mi][ni] = MFMA(a[mi], b, acc[mi][ni]);
        }
    }
    int g = lane >> 4, cl = lane & 15;
    // V = hh + X, accumulate row stats over this wave's 64 cols
#pragma unroll
    for (int mi = 0; mi < 4; mi++)
#pragma unroll
        for (int r = 0; r < 4; r++) {
            float s = 0.f, q = 0.f;
            int row = mi * 16 + g * 4 + r;
#pragma unroll
            for (int ni = 0; ni < 4; ni++) {
                int col = c0 + ni * 16 + cl;
                float v = acc[mi][ni][r] + b2f(x[(size_t)(r0 + row) * 256 + col]);
                acc[mi][ni][r] = v;
                s += v; q += v * v;
            }
            for (int m = 1; m < 16; m <<= 1) {
                s += __shfl_xor(s, m, 64);
                q += __shfl_xor(q, m, 64);
            }
            if (cl == 0) { redS[row][wv] = s; redQ[row][wv] = q; }
        }
    __syncthreads();

    float lw[4], lb[4];
#pragma unroll
    for (int ni = 0; ni < 4; ni++) {
        lw[ni] = lnw[c0 + ni * 16 + cl];
        lb[ni] = lnb[c0 + ni * 16 + cl];
    }
#pragma unroll
    for (int mi = 0; mi < 4; mi++)
#pragma unroll
        for (int r = 0; r < 4; r++) {
            int row = mi * 16 + g * 4 + r;
            float S = redS[row][0] + redS[row][1] + redS[row][2] + redS[row][3];
            float Q = redQ[row][0] + redQ[row][1] + redQ[row][2] + redQ[row][3];
            float m = S * (1.f / 256.f);
            float rs = rsqrtf(Q * (1.f / 256.f) - m * m + 1e-5f);
#pragma unroll
            for (int ni = 0; ni < 4; ni++) {
                float y = (acc[mi][ni][r] - m) * rs * lw[ni] + lb[ni];
                h3[(size_t)(r0 + row) * 256 + c0 + ni * 16 + cl] = f2bu(y);
            }
        }
}

// ---------------------------------------------------------------------------
// Kernel H (MFMA): out = h3 @ out_w^T + out_b, 256 -> 1024, f32 out
// grid (1024, 4); wave computes 64 rows x 64 cols
// ---------------------------------------------------------------------------
__global__ __launch_bounds__(256) void k_out_mfma(const u16* __restrict__ h3,
                                                  const float* __restrict__ w,
                                                  const float* __restrict__ bias,
                                                  float* __restrict__ out) {
    int lane = threadIdx.x & 63, wv = threadIdx.x >> 6;
    int r0 = blockIdx.x * 64;
    int c0 = blockIdx.y * 256 + wv * 64;
    f32x4 acc[4][4] = {};
    for (int ks = 0; ks < 8; ks++) {
        int k0 = ks * 32;
        bf16x8 a[4];
#pragma unroll
        for (int mi = 0; mi < 4; mi++) a[mi] = ldfrag(h3, r0 + mi * 16 + (lane & 15), k0, lane);
#pragma unroll
        for (int ni = 0; ni < 4; ni++) {
            bf16x8 b = ldfragf(w, c0 + ni * 16 + (lane & 15), k0, lane);
#pragma unroll
            for (int mi = 0; mi < 4; mi++) acc[mi][ni] = MFMA(a[mi], b, acc[mi][ni]);
        }
    }
    int g = lane >> 4, cl = lane & 15;
#pragma unroll
    for (int ni = 0; ni < 4; ni++) {
        float bv = bias[c0 + ni * 16 + cl];
#pragma unroll
        for (int mi = 0; mi < 4; mi++)
#pragma unroll
            for (int r = 0; r < 4; r++)
                out[(size_t)(r0 + mi * 16 + g * 4 + r) * VV + c0 + ni * 16 + cl] =
                    acc[mi][ni][r] + bv;
    }
}

// ---------------------------------------------------------------------------
extern "C" void kernel_launch(void* const* d_in, const int* in_sizes, int n_in,
                              void* d_out, int out_size, void* d_ws, size_t ws_size,
                              hipStream_t stream) {
    const int* chars        = (const int*)d_in[0];
    const float* byte_embed = (const float*)d_in[1];
    const float* table0     = (const float*)d_in[2];
    const float* table1     = (const float*)d_in[3];
    const float* table2     = (const float*)d_in[4];
    const float* table3     = (const float*)d_in[5];
    const float* cond_w     = (const float*)d_in[6];
    const float* conv_w     = (const float*)d_in[7];
    const float* conv_b     = (const float*)d_in[8];
    const float* gate_w     = (const float*)d_in[9];
    const float* gate_b     = (const float*)d_in[10];
    const float* inpr_w     = (const float*)d_in[11];
    const float* inpr_b     = (const float*)d_in[12];
    const float* outpr_w    = (const float*)d_in[13];
    const float* outpr_b    = (const float*)d_in[14];
    const float* scan_ln_w  = (const float*)d_in[15];
    const float* scan_ln_b  = (const float*)d_in[16];
    const float* inp_w      = (const float*)d_in[17];
    const float* inp_b      = (const float*)d_in[18];
    const float* r_w1       = (const float*)d_in[19];
    const float* r_w2       = (const float*)d_in[20];
    const float* r_proj     = (const float*)d_in[21];
    const float* r_ln_w     = (const float*)d_in[22];
    const float* r_ln_b     = (const float*)d_in[23];
    const float* out_w      = (const float*)d_in[24];
    const float* out_b      = (const float*)d_in[25];

    // ws layout (peak 64 MB, within proven bounds). Lifetimes:
    //   raw [k_hash..k_feat), hf [k_feat..k_post], Ag/Dr [k_gates..k_scan],
    //   st [k_scan..k_post], h1 [k_post..k_mlp1]
    //   h2b @0      (32MB) overlaps raw/hf/Ag/Dr-head: all dead by k_mlp1
    //   Ub/h3b @32MB (32MB) overlaps Dr-tail/st/h1-head: all dead by k_gemm_u;
    //   h3b aliases Ub row-for-row (safe: block stores own rows after reads)
    char* ws = (char*)d_ws;
    float* raw = (float*)(ws + 0);
    float* hf  = (float*)(ws + 2097152);
    float* Ag  = (float*)(ws + 23068672);
    float* Dr  = (float*)(ws + 31457280);
    float* st  = (float*)(ws + 39845888);
    float* h1  = (float*)(ws + 48234496);
    u16*   h2b = (u16*)(ws + 0);
    u16*   Ub  = (u16*)(ws + 33554432);
    u16*   h3b = (u16*)(ws + 33554432);
    float* out = (float*)d_out;

    k_hash <<<256, 256, 0, stream>>>(chars, table0, table1, table2, table3, cond_w, raw);
    k_feat <<<256, 256, 0, stream>>>(chars, byte_embed, raw, conv_w, conv_b, hf);
    k_gates<<<1024, 256, 0, stream>>>(hf, gate_w, gate_b, inpr_w, inpr_b, Ag, Dr);
    k_scan <<<4, 256, 0, stream>>>(Ag, Dr, st);
    k_post <<<256, 256, 0, stream>>>(st, hf, outpr_w, outpr_b, scan_ln_w, scan_ln_b, h1);
    k_mlp1 <<<1024, 256, 0, stream>>>(h1, inp_w, inp_b, h2b);
    k_gemm_u   <<<dim3(1024, 2), 256, 0, stream>>>(h2b, r_w1, r_w2, Ub);
    k_gemm_proj<<<1024, 256, 0, stream>>>(Ub, r_proj, h2b, r_ln_w, r_ln_b, h3b);
    k_out_mfma <<<dim3(1024, 4), 256, 0, stream>>>(h3b, out_w, out_b, out);
}

// Round 3
// 578.365 us; speedup vs baseline: 6.1937x; 1.3650x over previous
//
#include <hip/hip_runtime.h>

#define BB 32
#define TT 2048
#define SS 32
#define DD 80
#define HH 256
#define VV 1024
#define EBD 64

typedef unsigned short u16;
typedef __attribute__((ext_vector_type(8))) __bf16 bf16x8;
typedef __attribute__((ext_vector_type(4))) float f32x4;

#define MFMA(a, b, c) __builtin_amdgcn_mfma_f32_16x16x32_bf16(a, b, c, 0, 0, 0)

__device__ inline u16 f2bu(float f) {
    unsigned u = __float_as_uint(f);
    return (u16)((u + 0x7FFFu + ((u >> 16) & 1u)) >> 16);
}
__device__ inline __bf16 f2b(float f) {
    u16 r = f2bu(f);
    return __builtin_bit_cast(__bf16, r);
}
__device__ inline float b2f(u16 h) { return __uint_as_float(((unsigned)h) << 16); }

// A/B fragment (16 rows x 32 k) from bf16 row-major [.][256]; row includes lane&15
__device__ inline bf16x8 ldfrag(const u16* base, int row, int k0, int lane) {
    return *(const bf16x8*)(base + (size_t)row * 256 + k0 + ((lane >> 4) << 3));
}
// Same fragment from f32 row-major [.][256], converted in-register
__device__ inline bf16x8 ldfragf(const float* base, int row, int k0, int lane) {
    const float* p = base + (size_t)row * 256 + k0 + ((lane >> 4) << 3);
    f32x4 w0 = *(const f32x4*)p;
    f32x4 w1 = *(const f32x4*)(p + 4);
    bf16x8 b;
    b[0] = f2b(w0[0]); b[1] = f2b(w0[1]); b[2] = f2b(w0[2]); b[3] = f2b(w0[3]);
    b[4] = f2b(w1[0]); b[5] = f2b(w1[1]); b[6] = f2b(w1[2]); b[7] = f2b(w1[3]);
    return b;
}

// ---------------------------------------------------------------------------
// Kernel A: polynomial rolling hashes + table gathers + conditioned long keys
// ---------------------------------------------------------------------------
__global__ __launch_bounds__(256) void k_hash(const int* __restrict__ tok,
                                              const float* __restrict__ t0,
                                              const float* __restrict__ t1,
                                              const float* __restrict__ t2,
                                              const float* __restrict__ t3,
                                              const float* __restrict__ cond_w,
                                              float* __restrict__ raw) {
    int idx = blockIdx.x * 256 + threadIdx.x;
    if (idx >= BB * TT) return;
    int b = idx / TT, t = idx % TT;
    const int* tr = tok + b * TT;

    unsigned long long tv[8];
#pragma unroll
    for (int i = 0; i < 8; i++) {
        int ts = t - 1 - i;
        tv[i] = (ts >= 0) ? (unsigned long long)(unsigned)tr[ts] : 0ull;
    }
    const unsigned long long P[8] = {2654435761ull, 2246822519ull, 3266489917ull,
                                     2028178513ull, 1220703125ull, 1610612741ull,
                                     805306457ull, 402653189ull};
    unsigned long long x = 0ull;
    x ^= tv[0] * P[0]; unsigned long long k0 = x % 2000000ull;
    x ^= tv[1] * P[1]; unsigned long long k1 = x % 2000000ull;
    x ^= tv[2] * P[2]; x ^= tv[3] * P[3]; unsigned long long k2 = x % 2000000ull;
    x ^= tv[4] * P[4]; x ^= tv[5] * P[5];
    x ^= tv[6] * P[6]; x ^= tv[7] * P[7]; unsigned long long k3 = x % 2000000ull;

    float f0 = t0[k0 * 2], f1 = t0[k0 * 2 + 1];
    float f2 = t1[k1 * 2], f3 = t1[k1 * 2 + 1];

    unsigned long long ck = 0ull;
#pragma unroll
    for (int j = 0; j < 8; j++) {
        float lg = f0 * cond_w[j * 4 + 0] + f1 * cond_w[j * 4 + 1] +
                   f2 * cond_w[j * 4 + 2] + f3 * cond_w[j * 4 + 3];
        if (lg > 0.f) ck ^= P[j];
    }
    unsigned long long lk2 = (k2 ^ ck) % 2000000ull;
    unsigned long long lk3 = (k3 ^ ck) % 2000000ull;

    float* o = raw + (size_t)idx * 8;
    o[0] = f0; o[1] = f1; o[2] = f2; o[3] = f3;
    o[4] = t2[lk2 * 2]; o[5] = t2[lk2 * 2 + 1];
    o[6] = t3[lk3 * 2]; o[7] = t3[lk3 * 2 + 1];
}

// ---------------------------------------------------------------------------
// Kernel B: causal depthwise conv + silu, assemble h[b,t,80]
// ---------------------------------------------------------------------------
__global__ __launch_bounds__(256) void k_feat(const int* __restrict__ tok,
                                              const float* __restrict__ be,
                                              const float* __restrict__ raw,
                                              const float* __restrict__ conv_w,
                                              const float* __restrict__ conv_b,
                                              float* __restrict__ hf) {
    int idx = blockIdx.x * 256 + threadIdx.x;
    if (idx >= BB * TT) return;
    int b = idx / TT, t = idx % TT;
    const int* tr = tok + b * TT;
    float* o = hf + (size_t)idx * DD;

    int tk = tr[t];
    const float* ber = be + (size_t)tk * EBD;
#pragma unroll 8
    for (int d = 0; d < EBD; d++) o[d] = ber[d];

#pragma unroll
    for (int c = 0; c < 8; c++) {
        float acc = conv_b[c];
#pragma unroll
        for (int k = 0; k < 8; k++) {
            int ts = t - 7 + k;
            if (ts >= 0) acc += conv_w[c * 8 + k] * raw[((size_t)(b * TT + ts)) * 8 + c];
        }
        o[64 + c] = acc / (1.f + expf(-acc));
    }

#pragma unroll
    for (int k = 1; k <= 8; k++) {
        float m = (t >= k && tr[t] == tr[t - k]) ? 1.f : 0.f;
        o[71 + k] = m;
    }
}

// ---------------------------------------------------------------------------
// Kernel C: scan gates
// ---------------------------------------------------------------------------
__global__ __launch_bounds__(256) void k_gates(const float* __restrict__ hf,
                                               const float* __restrict__ gw,
                                               const float* __restrict__ gb,
                                               const float* __restrict__ iw,
                                               const float* __restrict__ ib,
                                               float* __restrict__ Ag,
                                               float* __restrict__ Dr) {
    __shared__ float xs[64][DD];
    int blk = blockIdx.x;
    int b = blk >> 5;
    int t0 = (blk & 31) << 6;
    const float* src = hf + ((size_t)(b * TT + t0)) * DD;
    for (int i = threadIdx.x; i < 64 * DD; i += 256) xs[i / DD][i % DD] = src[i];
    __syncthreads();

    for (int p = threadIdx.x; p < 64 * SS; p += 256) {
        int s = p & 31, tt = p >> 5;
        float ga = gb[s], ia = ib[s];
        for (int d = 0; d < DD; d++) {
            float xv = xs[tt][d];
            ga += xv * gw[s * DD + d];
            ia += xv * iw[s * DD + d];
        }
        float g = 1.f / (1.f + expf(-ga));
        float drv = (1.f - g) * ia;
        size_t oo = ((size_t)(b * SS + s)) * TT + t0 + tt;
        Ag[oo] = g;
        Dr[oo] = drv;
    }
}

// ---------------------------------------------------------------------------
// Kernel D: parallel chunked scan. One wave (64 lanes) per (b,s) series;
// lane c owns chunk c. Within-chunk 32-step pass replicates reference clamp
// semantics exactly; across chunks the carry is h' = A_c*h + B_c, composed
// by a wave-level Hillis-Steele scan of (A,B) pairs. Reordering error ~A_c
// (= prod of 32 sigmoids ~ 2^-32) -- negligible.
// ---------------------------------------------------------------------------
__global__ __launch_bounds__(64) void k_scan_par(const float* __restrict__ Ag,
                                                 const float* __restrict__ Dr,
                                                 float* __restrict__ st) {
    int bs = blockIdx.x;                  // b*SS + s
    int b = bs >> 5, s = bs & 31;
    int c = threadIdx.x;                  // chunk index 0..63
    const float* ar = Ag + (size_t)bs * TT + c * 32;
    const float* dr = Dr + (size_t)bs * TT + c * 32;

    float ca[32], cw[32];
    float lacc = 0.f, wacc = 0.f;
#pragma unroll
    for (int k = 0; k < 32; k += 4) {
        f32x4 av = *(const f32x4*)(ar + k);
        f32x4 dv = *(const f32x4*)(dr + k);
#pragma unroll
        for (int j = 0; j < 4; j++) {
            lacc += logf(fmaxf(av[j], 1e-6f));
            float cav = expf(lacc);
            ca[k + j] = cav;
            wacc += dv[j] / fmaxf(cav, 1e-8f);
            cw[k + j] = wacc;
        }
    }

    // inclusive scan of linear maps: P_c = f_c ∘ ... ∘ f_0
    float A = ca[31];
    float Bc = ca[31] * wacc;
    for (int off = 1; off < 64; off <<= 1) {
        float Ap = __shfl_up(A, off, 64);
        float Bp = __shfl_up(Bc, off, 64);
        if (c >= off) {
            Bc = A * Bp + Bc;   // uses old A (self) — apply prev first
            A = A * Ap;
        }
    }
    float h0 = __shfl_up(Bc, 1, 64);      // carry entering chunk c = B_incl[c-1]
    if (c == 0) h0 = 0.f;

    float* op = st + ((size_t)(b * TT + c * 32)) * SS + s;
#pragma unroll
    for (int k = 0; k < 32; k++)
        op[(size_t)k * SS] = ca[k] * (h0 + cw[k]);
}

// ---------------------------------------------------------------------------
// Kernel E: y = states @ outpr_w^T + ob ; h1 = LN(hf + y)
// ---------------------------------------------------------------------------
__global__ __launch_bounds__(256) void k_post(const float* __restrict__ st,
                                              const float* __restrict__ hf,
                                              const float* __restrict__ ow,
                                              const float* __restrict__ ob,
                                              const float* __restrict__ lnw,
                                              const float* __restrict__ lnb,
                                              float* __restrict__ h1) {
    int idx = blockIdx.x * 256 + threadIdx.x;
    if (idx >= BB * TT) return;
    const float* sp = st + (size_t)idx * SS;
    float sv[SS];
#pragma unroll
    for (int i = 0; i < SS; i++) sv[i] = sp[i];
    const float* x = hf + (size_t)idx * DD;

    float s1 = 0.f, s2 = 0.f;
    for (int d = 0; d < DD; d++) {
        float acc = ob[d];
#pragma unroll
        for (int i = 0; i < SS; i++) acc += sv[i] * ow[d * SS + i];
        float v = acc + x[d];
        s1 += v; s2 += v * v;
    }
    float m = s1 * (1.f / DD);
    float var = s2 * (1.f / DD) - m * m;
    float rs = rsqrtf(var + 1e-5f);
    for (int d = 0; d < DD; d++) {
        float acc = ob[d];
#pragma unroll
        for (int i = 0; i < SS; i++) acc += sv[i] * ow[d * SS + i];
        float v = acc + x[d];
        h1[(size_t)idx * DD + d] = (v - m) * rs * lnw[d] + lnb[d];
    }
}

// ---------------------------------------------------------------------------
// Kernel F: h2 = silu(h1 @ inp_w^T + inp_b), 80 -> 256, bf16 out
// ---------------------------------------------------------------------------
__global__ __launch_bounds__(256) void k_mlp1(const float* __restrict__ h1,
                                              const float* __restrict__ w,
                                              const float* __restrict__ bias,
                                              u16* __restrict__ h2) {
    __shared__ float xs[64][DD];
    int blk = blockIdx.x;
    int b = blk >> 5;
    int t0 = (blk & 31) << 6;
    const float* src = h1 + ((size_t)(b * TT + t0)) * DD;
    for (int i = threadIdx.x; i < 64 * DD; i += 256) xs[i / DD][i % DD] = src[i];
    __syncthreads();

    int j = threadIdx.x;
    float bj = bias[j];
    for (int tt0 = 0; tt0 < 64; tt0 += 16) {
        float acc[16];
#pragma unroll
        for (int r = 0; r < 16; r++) acc[r] = bj;
        for (int d = 0; d < DD; d++) {
            float wv = w[j * DD + d];
#pragma unroll
            for (int r = 0; r < 16; r++) acc[r] += xs[tt0 + r][d] * wv;
        }
#pragma unroll
        for (int r = 0; r < 16; r++) {
            float v = acc[r];
            h2[((size_t)(b * TT + t0 + tt0 + r)) * HH + j] = f2bu(v / (1.f + expf(-v)));
        }
    }
}

// ---------------------------------------------------------------------------
// Kernel G1 (MFMA): U = silu(X@w1^T) * (X@w2^T), bf16 in/out, K=256
// ---------------------------------------------------------------------------
__global__ __launch_bounds__(256) void k_gemm_u(const u16* __restrict__ x,
                                                const float* __restrict__ w1,
                                                const float* __restrict__ w2,
                                                u16* __restrict__ U) {
    int lane = threadIdx.x & 63, wv = threadIdx.x >> 6;
    int r0 = blockIdx.x * 64;
    int c0 = blockIdx.y * 128 + wv * 32;
    f32x4 a1[4][2] = {}, a2[4][2] = {};
    for (int ks = 0; ks < 8; ks++) {
        int k0 = ks * 32;
        bf16x8 a[4];
#pragma unroll
        for (int mi = 0; mi < 4; mi++) a[mi] = ldfrag(x, r0 + mi * 16 + (lane & 15), k0, lane);
#pragma unroll
        for (int ni = 0; ni < 2; ni++) {
            bf16x8 b1 = ldfragf(w1, c0 + ni * 16 + (lane & 15), k0, lane);
            bf16x8 b2 = ldfragf(w2, c0 + ni * 16 + (lane & 15), k0, lane);
#pragma unroll
            for (int mi = 0; mi < 4; mi++) {
                a1[mi][ni] = MFMA(a[mi], b1, a1[mi][ni]);
                a2[mi][ni] = MFMA(a[mi], b2, a2[mi][ni]);
            }
        }
    }
    int g = lane >> 4, cl = lane & 15;
#pragma unroll
    for (int mi = 0; mi < 4; mi++)
#pragma unroll
        for (int ni = 0; ni < 2; ni++)
#pragma unroll
            for (int r = 0; r < 4; r++) {
                float v1 = a1[mi][ni][r], v2 = a2[mi][ni][r];
                float u = v1 / (1.f + expf(-v1)) * v2;
                U[(size_t)(r0 + mi * 16 + g * 4 + r) * 256 + c0 + ni * 16 + cl] = f2bu(u);
            }
}

// ---------------------------------------------------------------------------
// Kernel G2 (MFMA): hh = U@wp^T; V = hh + X; h3 = LN(V), bf16 out
// ---------------------------------------------------------------------------
__global__ __launch_bounds__(256) void k_gemm_proj(const u16* __restrict__ U,
                                                   const float* __restrict__ wp,
                                                   const u16* __restrict__ x,
                                                   const float* __restrict__ lnw,
                                                   const float* __restrict__ lnb,
                                                   u16* __restrict__ h3) {
    __shared__ float redS[64][4], redQ[64][4];
    int lane = threadIdx.x & 63, wv = threadIdx.x >> 6;
    int r0 = blockIdx.x * 64;
    int c0 = wv * 64;
    f32x4 acc[4][4] = {};
    for (int ks = 0; ks < 8; ks++) {
        int k0 = ks * 32;
        bf16x8 a[4];
#pragma unroll
        for (int mi = 0; mi < 4; mi++) a[mi] = ldfrag(U, r0 + mi * 16 + (lane & 15), k0, lane);
#pragma unroll
        for (int ni = 0; ni < 4; ni++) {
            bf16x8 b = ldfragf(wp, c0 + ni * 16 + (lane & 15), k0, lane);
#pragma unroll
            for (int mi = 0; mi < 4; mi++) acc[mi][ni] = MFMA(a[mi], b, acc[mi][ni]);
        }
    }
    int g = lane >> 4, cl = lane & 15;
#pragma unroll
    for (int mi = 0; mi < 4; mi++)
#pragma unroll
        for (int r = 0; r < 4; r++) {
            float s = 0.f, q = 0.f;
            int row = mi * 16 + g * 4 + r;
#pragma unroll
            for (int ni = 0; ni < 4; ni++) {
                int col = c0 + ni * 16 + cl;
                float v = acc[mi][ni][r] + b2f(x[(size_t)(r0 + row) * 256 + col]);
                acc[mi][ni][r] = v;
                s += v; q += v * v;
            }
            for (int m = 1; m < 16; m <<= 1) {
                s += __shfl_xor(s, m, 64);
                q += __shfl_xor(q, m, 64);
            }
            if (cl == 0) { redS[row][wv] = s; redQ[row][wv] = q; }
        }
    __syncthreads();

    float lw[4], lb[4];
#pragma unroll
    for (int ni = 0; ni < 4; ni++) {
        lw[ni] = lnw[c0 + ni * 16 + cl];
        lb[ni] = lnb[c0 + ni * 16 + cl];
    }
#pragma unroll
    for (int mi = 0; mi < 4; mi++)
#pragma unroll
        for (int r = 0; r < 4; r++) {
            int row = mi * 16 + g * 4 + r;
            float S = redS[row][0] + redS[row][1] + redS[row][2] + redS[row][3];
            float Q = redQ[row][0] + redQ[row][1] + redQ[row][2] + redQ[row][3];
            float m = S * (1.f / 256.f);
            float rs = rsqrtf(Q * (1.f / 256.f) - m * m + 1e-5f);
#pragma unroll
            for (int ni = 0; ni < 4; ni++) {
                float y = (acc[mi][ni][r] - m) * rs * lw[ni] + lb[ni];
                h3[(size_t)(r0 + row) * 256 + c0 + ni * 16 + cl] = f2bu(y);
            }
        }
}

// ---------------------------------------------------------------------------
// Kernel H (MFMA): out = h3 @ out_w^T + out_b, 256 -> 1024, f32 out
// ---------------------------------------------------------------------------
__global__ __launch_bounds__(256) void k_out_mfma(const u16* __restrict__ h3,
                                                  const float* __restrict__ w,
                                                  const float* __restrict__ bias,
                                                  float* __restrict__ out) {
    int lane = threadIdx.x & 63, wv = threadIdx.x >> 6;
    int r0 = blockIdx.x * 64;
    int c0 = blockIdx.y * 256 + wv * 64;
    f32x4 acc[4][4] = {};
    for (int ks = 0; ks < 8; ks++) {
        int k0 = ks * 32;
        bf16x8 a[4];
#pragma unroll
        for (int mi = 0; mi < 4; mi++) a[mi] = ldfrag(h3, r0 + mi * 16 + (lane & 15), k0, lane);
#pragma unroll
        for (int ni = 0; ni < 4; ni++) {
            bf16x8 b = ldfragf(w, c0 + ni * 16 + (lane & 15), k0, lane);
#pragma unroll
            for (int mi = 0; mi < 4; mi++) acc[mi][ni] = MFMA(a[mi], b, acc[mi][ni]);
        }
    }
    int g = lane >> 4, cl = lane & 15;
#pragma unroll
    for (int ni = 0; ni < 4; ni++) {
        float bv = bias[c0 + ni * 16 + cl];
#pragma unroll
        for (int mi = 0; mi < 4; mi++)
#pragma unroll
            for (int r = 0; r < 4; r++)
                out[(size_t)(r0 + mi * 16 + g * 4 + r) * VV + c0 + ni * 16 + cl] =
                    acc[mi][ni][r] + bv;
    }
}

// ---------------------------------------------------------------------------
extern "C" void kernel_launch(void* const* d_in, const int* in_sizes, int n_in,
                              void* d_out, int out_size, void* d_ws, size_t ws_size,
                              hipStream_t stream) {
    const int* chars        = (const int*)d_in[0];
    const float* byte_embed = (const float*)d_in[1];
    const float* table0     = (const float*)d_in[2];
    const float* table1     = (const float*)d_in[3];
    const float* table2     = (const float*)d_in[4];
    const float* table3     = (const float*)d_in[5];
    const float* cond_w     = (const float*)d_in[6];
    const float* conv_w     = (const float*)d_in[7];
    const float* conv_b     = (const float*)d_in[8];
    const float* gate_w     = (const float*)d_in[9];
    const float* gate_b     = (const float*)d_in[10];
    const float* inpr_w     = (const float*)d_in[11];
    const float* inpr_b     = (const float*)d_in[12];
    const float* outpr_w    = (const float*)d_in[13];
    const float* outpr_b    = (const float*)d_in[14];
    const float* scan_ln_w  = (const float*)d_in[15];
    const float* scan_ln_b  = (const float*)d_in[16];
    const float* inp_w      = (const float*)d_in[17];
    const float* inp_b      = (const float*)d_in[18];
    const float* r_w1       = (const float*)d_in[19];
    const float* r_w2       = (const float*)d_in[20];
    const float* r_proj     = (const float*)d_in[21];
    const float* r_ln_w     = (const float*)d_in[22];
    const float* r_ln_b     = (const float*)d_in[23];
    const float* out_w      = (const float*)d_in[24];
    const float* out_b      = (const float*)d_in[25];

    char* ws = (char*)d_ws;
    float* raw = (float*)(ws + 0);
    float* hf  = (float*)(ws + 2097152);
    float* Ag  = (float*)(ws + 23068672);
    float* Dr  = (float*)(ws + 31457280);
    float* st  = (float*)(ws + 39845888);
    float* h1  = (float*)(ws + 48234496);
    u16*   h2b = (u16*)(ws + 0);
    u16*   Ub  = (u16*)(ws + 33554432);
    u16*   h3b = (u16*)(ws + 33554432);
    float* out = (float*)d_out;

    k_hash <<<256, 256, 0, stream>>>(chars, table0, table1, table2, table3, cond_w, raw);
    k_feat <<<256, 256, 0, stream>>>(chars, byte_embed, raw, conv_w, conv_b, hf);
    k_gates<<<1024, 256, 0, stream>>>(hf, gate_w, gate_b, inpr_w, inpr_b, Ag, Dr);
    k_scan_par<<<1024, 64, 0, stream>>>(Ag, Dr, st);
    k_post <<<256, 256, 0, stream>>>(st, hf, outpr_w, outpr_b, scan_ln_w, scan_ln_b, h1);
    k_mlp1 <<<1024, 256, 0, stream>>>(h1, inp_w, inp_b, h2b);
    k_gemm_u   <<<dim3(1024, 2), 256, 0, stream>>>(h2b, r_w1, r_w2, Ub);
    k_gemm_proj<<<1024, 256, 0, stream>>>(Ub, r_proj, h2b, r_ln_w, r_ln_b, h3b);
    k_out_mfma <<<dim3(1024, 4), 256, 0, stream>>>(h3b, out_w, out_b, out);
}

// Round 4
// 522.764 us; speedup vs baseline: 6.8525x; 1.1064x over previous
//
#include <hip/hip_runtime.h>

#define BB 32
#define TT 2048
#define SS 32
#define DD 80
#define HH 256
#define VV 1024
#define EBD 64

typedef unsigned short u16;
typedef __attribute__((ext_vector_type(8))) __bf16 bf16x8;
typedef __attribute__((ext_vector_type(4))) float f32x4;

#define MFMA(a, b, c) __builtin_amdgcn_mfma_f32_16x16x32_bf16(a, b, c, 0, 0, 0)

__device__ inline u16 f2bu(float f) {
    unsigned u = __float_as_uint(f);
    return (u16)((u + 0x7FFFu + ((u >> 16) & 1u)) >> 16);
}
__device__ inline __bf16 f2b(float f) {
    u16 r = f2bu(f);
    return __builtin_bit_cast(__bf16, r);
}
__device__ inline float b2f(u16 h) { return __uint_as_float(((unsigned)h) << 16); }

// A/B fragment (16 rows x 32 k) from bf16 row-major [.][256]
__device__ inline bf16x8 ldfrag(const u16* base, int row, int k0, int lane) {
    return *(const bf16x8*)(base + (size_t)row * 256 + k0 + ((lane >> 4) << 3));
}

// ---------------------------------------------------------------------------
// Kernel P: convert GEMM weights f32 -> bf16 once per launch
// layout in wbf: r_w1[0,64K) r_w2[64K,128K) r_proj[128K,192K) out_w[192K,448K)
// ---------------------------------------------------------------------------
__global__ __launch_bounds__(256) void k_prep(const float* __restrict__ w1,
                                              const float* __restrict__ w2,
                                              const float* __restrict__ wp,
                                              const float* __restrict__ ow,
                                              u16* __restrict__ wbf) {
    int i = blockIdx.x * 256 + threadIdx.x;
    if (i >= 458752) return;
    float v;
    if (i < 65536) v = w1[i];
    else if (i < 131072) v = w2[i - 65536];
    else if (i < 196608) v = wp[i - 131072];
    else v = ow[i - 196608];
    wbf[i] = f2bu(v);
}

// ---------------------------------------------------------------------------
// Kernel A: polynomial rolling hashes + table gathers + conditioned long keys
// ---------------------------------------------------------------------------
__global__ __launch_bounds__(256) void k_hash(const int* __restrict__ tok,
                                              const float* __restrict__ t0,
                                              const float* __restrict__ t1,
                                              const float* __restrict__ t2,
                                              const float* __restrict__ t3,
                                              const float* __restrict__ cond_w,
                                              float* __restrict__ raw) {
    int idx = blockIdx.x * 256 + threadIdx.x;
    if (idx >= BB * TT) return;
    int b = idx / TT, t = idx % TT;
    const int* tr = tok + b * TT;

    unsigned long long tv[8];
#pragma unroll
    for (int i = 0; i < 8; i++) {
        int ts = t - 1 - i;
        tv[i] = (ts >= 0) ? (unsigned long long)(unsigned)tr[ts] : 0ull;
    }
    const unsigned long long P[8] = {2654435761ull, 2246822519ull, 3266489917ull,
                                     2028178513ull, 1220703125ull, 1610612741ull,
                                     805306457ull, 402653189ull};
    unsigned long long x = 0ull;
    x ^= tv[0] * P[0]; unsigned long long k0 = x % 2000000ull;
    x ^= tv[1] * P[1]; unsigned long long k1 = x % 2000000ull;
    x ^= tv[2] * P[2]; x ^= tv[3] * P[3]; unsigned long long k2 = x % 2000000ull;
    x ^= tv[4] * P[4]; x ^= tv[5] * P[5];
    x ^= tv[6] * P[6]; x ^= tv[7] * P[7]; unsigned long long k3 = x % 2000000ull;

    float f0 = t0[k0 * 2], f1 = t0[k0 * 2 + 1];
    float f2 = t1[k1 * 2], f3 = t1[k1 * 2 + 1];

    unsigned long long ck = 0ull;
#pragma unroll
    for (int j = 0; j < 8; j++) {
        float lg = f0 * cond_w[j * 4 + 0] + f1 * cond_w[j * 4 + 1] +
                   f2 * cond_w[j * 4 + 2] + f3 * cond_w[j * 4 + 3];
        if (lg > 0.f) ck ^= P[j];
    }
    unsigned long long lk2 = (k2 ^ ck) % 2000000ull;
    unsigned long long lk3 = (k3 ^ ck) % 2000000ull;

    float* o = raw + (size_t)idx * 8;
    o[0] = f0; o[1] = f1; o[2] = f2; o[3] = f3;
    o[4] = t2[lk2 * 2]; o[5] = t2[lk2 * 2 + 1];
    o[6] = t3[lk3 * 2]; o[7] = t3[lk3 * 2 + 1];
}

// ---------------------------------------------------------------------------
// Kernel B: causal depthwise conv + silu, assemble h[b,t,80]
// ---------------------------------------------------------------------------
__global__ __launch_bounds__(256) void k_feat(const int* __restrict__ tok,
                                              const float* __restrict__ be,
                                              const float* __restrict__ raw,
                                              const float* __restrict__ conv_w,
                                              const float* __restrict__ conv_b,
                                              float* __restrict__ hf) {
    int idx = blockIdx.x * 256 + threadIdx.x;
    if (idx >= BB * TT) return;
    int b = idx / TT, t = idx % TT;
    const int* tr = tok + b * TT;
    float* o = hf + (size_t)idx * DD;

    int tk = tr[t];
    const float* ber = be + (size_t)tk * EBD;
#pragma unroll 8
    for (int d = 0; d < EBD; d++) o[d] = ber[d];

#pragma unroll
    for (int c = 0; c < 8; c++) {
        float acc = conv_b[c];
#pragma unroll
        for (int k = 0; k < 8; k++) {
            int ts = t - 7 + k;
            if (ts >= 0) acc += conv_w[c * 8 + k] * raw[((size_t)(b * TT + ts)) * 8 + c];
        }
        o[64 + c] = acc / (1.f + expf(-acc));
    }

#pragma unroll
    for (int k = 1; k <= 8; k++) {
        float m = (t >= k && tr[t] == tr[t - k]) ? 1.f : 0.f;
        o[71 + k] = m;
    }
}

// ---------------------------------------------------------------------------
// Kernel C: scan gates
// ---------------------------------------------------------------------------
__global__ __launch_bounds__(256) void k_gates(const float* __restrict__ hf,
                                               const float* __restrict__ gw,
                                               const float* __restrict__ gb,
                                               const float* __restrict__ iw,
                                               const float* __restrict__ ib,
                                               float* __restrict__ Ag,
                                               float* __restrict__ Dr) {
    __shared__ float xs[64][DD];
    int blk = blockIdx.x;
    int b = blk >> 5;
    int t0 = (blk & 31) << 6;
    const float* src = hf + ((size_t)(b * TT + t0)) * DD;
    for (int i = threadIdx.x; i < 64 * DD; i += 256) xs[i / DD][i % DD] = src[i];
    __syncthreads();

    for (int p = threadIdx.x; p < 64 * SS; p += 256) {
        int s = p & 31, tt = p >> 5;
        float ga = gb[s], ia = ib[s];
        for (int d = 0; d < DD; d++) {
            float xv = xs[tt][d];
            ga += xv * gw[s * DD + d];
            ia += xv * iw[s * DD + d];
        }
        float g = 1.f / (1.f + expf(-ga));
        float drv = (1.f - g) * ia;
        size_t oo = ((size_t)(b * SS + s)) * TT + t0 + tt;
        Ag[oo] = g;
        Dr[oo] = drv;
    }
}

// ---------------------------------------------------------------------------
// Kernel D: parallel chunked scan (wave-scan of per-chunk linear maps)
// ---------------------------------------------------------------------------
__global__ __launch_bounds__(64) void k_scan_par(const float* __restrict__ Ag,
                                                 const float* __restrict__ Dr,
                                                 float* __restrict__ st) {
    int bs = blockIdx.x;
    int b = bs >> 5, s = bs & 31;
    int c = threadIdx.x;
    const float* ar = Ag + (size_t)bs * TT + c * 32;
    const float* dr = Dr + (size_t)bs * TT + c * 32;

    float ca[32], cw[32];
    float lacc = 0.f, wacc = 0.f;
#pragma unroll
    for (int k = 0; k < 32; k += 4) {
        f32x4 av = *(const f32x4*)(ar + k);
        f32x4 dv = *(const f32x4*)(dr + k);
#pragma unroll
        for (int j = 0; j < 4; j++) {
            lacc += logf(fmaxf(av[j], 1e-6f));
            float cav = expf(lacc);
            ca[k + j] = cav;
            wacc += dv[j] / fmaxf(cav, 1e-8f);
            cw[k + j] = wacc;
        }
    }

    float A = ca[31];
    float Bc = ca[31] * wacc;
    for (int off = 1; off < 64; off <<= 1) {
        float Ap = __shfl_up(A, off, 64);
        float Bp = __shfl_up(Bc, off, 64);
        if (c >= off) {
            Bc = A * Bp + Bc;
            A = A * Ap;
        }
    }
    float h0 = __shfl_up(Bc, 1, 64);
    if (c == 0) h0 = 0.f;

    float* op = st + ((size_t)(b * TT + c * 32)) * SS + s;
#pragma unroll
    for (int k = 0; k < 32; k++)
        op[(size_t)k * SS] = ca[k] * (h0 + cw[k]);
}

// ---------------------------------------------------------------------------
// Kernel E: y = states @ outpr_w^T + ob ; h1 = LN(hf + y)  (bf16 out)
// ---------------------------------------------------------------------------
__global__ __launch_bounds__(256) void k_post(const float* __restrict__ st,
                                              const float* __restrict__ hf,
                                              const float* __restrict__ ow,
                                              const float* __restrict__ ob,
                                              const float* __restrict__ lnw,
                                              const float* __restrict__ lnb,
                                              u16* __restrict__ h1) {
    int idx = blockIdx.x * 256 + threadIdx.x;
    if (idx >= BB * TT) return;
    const float* sp = st + (size_t)idx * SS;
    float sv[SS];
#pragma unroll
    for (int i = 0; i < SS; i++) sv[i] = sp[i];
    const float* x = hf + (size_t)idx * DD;

    float s1 = 0.f, s2 = 0.f;
    for (int d = 0; d < DD; d++) {
        float acc = ob[d];
#pragma unroll
        for (int i = 0; i < SS; i++) acc += sv[i] * ow[d * SS + i];
        float v = acc + x[d];
        s1 += v; s2 += v * v;
    }
    float m = s1 * (1.f / DD);
    float var = s2 * (1.f / DD) - m * m;
    float rs = rsqrtf(var + 1e-5f);
    for (int d = 0; d < DD; d++) {
        float acc = ob[d];
#pragma unroll
        for (int i = 0; i < SS; i++) acc += sv[i] * ow[d * SS + i];
        float v = acc + x[d];
        h1[(size_t)idx * DD + d] = f2bu((v - m) * rs * lnw[d] + lnb[d]);
    }
}

// ---------------------------------------------------------------------------
// Kernel F: h2 = silu(h1 @ inp_w^T + inp_b), 80 -> 256, bf16 in/out
// ---------------------------------------------------------------------------
__global__ __launch_bounds__(256) void k_mlp1(const u16* __restrict__ h1,
                                              const float* __restrict__ w,
                                              const float* __restrict__ bias,
                                              u16* __restrict__ h2) {
    __shared__ float xs[64][DD];
    int blk = blockIdx.x;
    int b = blk >> 5;
    int t0 = (blk & 31) << 6;
    const u16* src = h1 + ((size_t)(b * TT + t0)) * DD;
    for (int i = threadIdx.x; i < 64 * DD; i += 256) xs[i / DD][i % DD] = b2f(src[i]);
    __syncthreads();

    int j = threadIdx.x;
    float bj = bias[j];
    for (int tt0 = 0; tt0 < 64; tt0 += 16) {
        float acc[16];
#pragma unroll
        for (int r = 0; r < 16; r++) acc[r] = bj;
        for (int d = 0; d < DD; d++) {
            float wv = w[j * DD + d];
#pragma unroll
            for (int r = 0; r < 16; r++) acc[r] += xs[tt0 + r][d] * wv;
        }
#pragma unroll
        for (int r = 0; r < 16; r++) {
            float v = acc[r];
            h2[((size_t)(b * TT + t0 + tt0 + r)) * HH + j] = f2bu(v / (1.f + expf(-v)));
        }
    }
}

// ---------------------------------------------------------------------------
// Kernel G1 (MFMA): U = silu(X@w1^T) * (X@w2^T), bf16 everywhere, K=256
// ---------------------------------------------------------------------------
__global__ __launch_bounds__(256) void k_gemm_u(const u16* __restrict__ x,
                                                const u16* __restrict__ w1,
                                                const u16* __restrict__ w2,
                                                u16* __restrict__ U) {
    int lane = threadIdx.x & 63, wv = threadIdx.x >> 6;
    int r0 = blockIdx.x * 64;
    int c0 = blockIdx.y * 128 + wv * 32;
    f32x4 a1[4][2] = {}, a2[4][2] = {};
    for (int ks = 0; ks < 8; ks++) {
        int k0 = ks * 32;
        bf16x8 a[4];
#pragma unroll
        for (int mi = 0; mi < 4; mi++) a[mi] = ldfrag(x, r0 + mi * 16 + (lane & 15), k0, lane);
#pragma unroll
        for (int ni = 0; ni < 2; ni++) {
            bf16x8 b1 = ldfrag(w1, c0 + ni * 16 + (lane & 15), k0, lane);
            bf16x8 b2 = ldfrag(w2, c0 + ni * 16 + (lane & 15), k0, lane);
#pragma unroll
            for (int mi = 0; mi < 4; mi++) {
                a1[mi][ni] = MFMA(a[mi], b1, a1[mi][ni]);
                a2[mi][ni] = MFMA(a[mi], b2, a2[mi][ni]);
            }
        }
    }
    int g = lane >> 4, cl = lane & 15;
#pragma unroll
    for (int mi = 0; mi < 4; mi++)
#pragma unroll
        for (int ni = 0; ni < 2; ni++)
#pragma unroll
            for (int r = 0; r < 4; r++) {
                float v1 = a1[mi][ni][r], v2 = a2[mi][ni][r];
                float u = v1 / (1.f + expf(-v1)) * v2;
                U[(size_t)(r0 + mi * 16 + g * 4 + r) * 256 + c0 + ni * 16 + cl] = f2bu(u);
            }
}

// ---------------------------------------------------------------------------
// Kernel G2+H fused (MFMA): hh = U@wp^T; V = hh + X; h3 = LN(V) -> swizzled LDS
// then out = h3 @ out_w^T + out_b directly from LDS. Saves the 64 MB h3
// round-trip and the redundant global A loads of the old k_out.
// LDS swizzle: u16 index = row*256 + (col ^ ((row&7)<<3)) — fragments of 8
// stay contiguous; rows spread across banks (<=2-way, free).
// ---------------------------------------------------------------------------
__global__ __launch_bounds__(256) void k_proj_out(const u16* __restrict__ U,
                                                  const u16* __restrict__ wp,
                                                  const u16* __restrict__ x,
                                                  const float* __restrict__ lnw,
                                                  const float* __restrict__ lnb,
                                                  const u16* __restrict__ ow,
                                                  const float* __restrict__ bias,
                                                  float* __restrict__ out) {
    __shared__ u16 hs[64 * 256];
    __shared__ float redS[64][4], redQ[64][4];
    int lane = threadIdx.x & 63, wv = threadIdx.x >> 6;
    int r0 = blockIdx.x * 64;
    int c0 = wv * 64;
    int g = lane >> 4, cl = lane & 15;

    // ---- phase 1: proj GEMM (K=256) ----
    f32x4 acc[4][4] = {};
    for (int ks = 0; ks < 8; ks++) {
        int k0 = ks * 32;
        bf16x8 a[4];
#pragma unroll
        for (int mi = 0; mi < 4; mi++) a[mi] = ldfrag(U, r0 + mi * 16 + (lane & 15), k0, lane);
#pragma unroll
        for (int ni = 0; ni < 4; ni++) {
            bf16x8 b = ldfrag(wp, c0 + ni * 16 + (lane & 15), k0, lane);
#pragma unroll
            for (int mi = 0; mi < 4; mi++) acc[mi][ni] = MFMA(a[mi], b, acc[mi][ni]);
        }
    }

    // residual + row stats
#pragma unroll
    for (int mi = 0; mi < 4; mi++)
#pragma unroll
        for (int r = 0; r < 4; r++) {
            float s = 0.f, q = 0.f;
            int row = mi * 16 + g * 4 + r;
#pragma unroll
            for (int ni = 0; ni < 4; ni++) {
                int col = c0 + ni * 16 + cl;
                float v = acc[mi][ni][r] + b2f(x[(size_t)(r0 + row) * 256 + col]);
                acc[mi][ni][r] = v;
                s += v; q += v * v;
            }
            for (int m = 1; m < 16; m <<= 1) {
                s += __shfl_xor(s, m, 64);
                q += __shfl_xor(q, m, 64);
            }
            if (cl == 0) { redS[row][wv] = s; redQ[row][wv] = q; }
        }
    __syncthreads();

    // LN -> swizzled LDS
    float lw[4], lb[4];
#pragma unroll
    for (int ni = 0; ni < 4; ni++) {
        lw[ni] = lnw[c0 + ni * 16 + cl];
        lb[ni] = lnb[c0 + ni * 16 + cl];
    }
#pragma unroll
    for (int mi = 0; mi < 4; mi++)
#pragma unroll
        for (int r = 0; r < 4; r++) {
            int row = mi * 16 + g * 4 + r;
            float S = redS[row][0] + redS[row][1] + redS[row][2] + redS[row][3];
            float Q = redQ[row][0] + redQ[row][1] + redQ[row][2] + redQ[row][3];
            float m = S * (1.f / 256.f);
            float rs = rsqrtf(Q * (1.f / 256.f) - m * m + 1e-5f);
#pragma unroll
            for (int ni = 0; ni < 4; ni++) {
                int col = c0 + ni * 16 + cl;
                float y = (acc[mi][ni][r] - m) * rs * lw[ni] + lb[ni];
                hs[row * 256 + (col ^ ((row & 7) << 3))] = f2bu(y);
            }
        }
    __syncthreads();

    // ---- phase 2: out GEMM, A from LDS, 4 col-groups of 256 ----
    for (int cg = 0; cg < 4; cg++) {
        int cc = cg * 256 + wv * 64;
        f32x4 acc2[4][4] = {};
        for (int ks = 0; ks < 8; ks++) {
            int k0 = ks * 32 + ((lane >> 4) << 3);
            bf16x8 a[4];
#pragma unroll
            for (int mi = 0; mi < 4; mi++) {
                int row = mi * 16 + (lane & 15);
                a[mi] = *(const bf16x8*)&hs[row * 256 + (k0 ^ ((row & 7) << 3))];
            }
#pragma unroll
            for (int ni = 0; ni < 4; ni++) {
                bf16x8 b = ldfrag(ow, cc + ni * 16 + (lane & 15), ks * 32, lane);
#pragma unroll
                for (int mi = 0; mi < 4; mi++) acc2[mi][ni] = MFMA(a[mi], b, acc2[mi][ni]);
            }
        }
#pragma unroll
        for (int ni = 0; ni < 4; ni++) {
            float bv = bias[cc + ni * 16 + cl];
#pragma unroll
            for (int mi = 0; mi < 4; mi++)
#pragma unroll
                for (int r = 0; r < 4; r++)
                    out[(size_t)(r0 + mi * 16 + g * 4 + r) * VV + cc + ni * 16 + cl] =
                        acc2[mi][ni][r] + bv;
        }
    }
}

// ---------------------------------------------------------------------------
extern "C" void kernel_launch(void* const* d_in, const int* in_sizes, int n_in,
                              void* d_out, int out_size, void* d_ws, size_t ws_size,
                              hipStream_t stream) {
    const int* chars        = (const int*)d_in[0];
    const float* byte_embed = (const float*)d_in[1];
    const float* table0     = (const float*)d_in[2];
    const float* table1     = (const float*)d_in[3];
    const float* table2     = (const float*)d_in[4];
    const float* table3     = (const float*)d_in[5];
    const float* cond_w     = (const float*)d_in[6];
    const float* conv_w     = (const float*)d_in[7];
    const float* conv_b     = (const float*)d_in[8];
    const float* gate_w     = (const float*)d_in[9];
    const float* gate_b     = (const float*)d_in[10];
    const float* inpr_w     = (const float*)d_in[11];
    const float* inpr_b     = (const float*)d_in[12];
    const float* outpr_w    = (const float*)d_in[13];
    const float* outpr_b    = (const float*)d_in[14];
    const float* scan_ln_w  = (const float*)d_in[15];
    const float* scan_ln_b  = (const float*)d_in[16];
    const float* inp_w      = (const float*)d_in[17];
    const float* inp_b      = (const float*)d_in[18];
    const float* r_w1       = (const float*)d_in[19];
    const float* r_w2       = (const float*)d_in[20];
    const float* r_proj     = (const float*)d_in[21];
    const float* r_ln_w     = (const float*)d_in[22];
    const float* r_ln_b     = (const float*)d_in[23];
    const float* out_w      = (const float*)d_in[24];
    const float* out_b      = (const float*)d_in[25];

    // ws layout with lifetimes (peak 68.2 MB):
    //   wbf  [0, 0.9M)        prep..end (persistent bf16 weights)
    //   hf   [1M, 24.1M)      feat..post
    //   raw  [24.1M, 26.2M)   hash..feat   (inside later Ag region)
    //   Ag   [24.1M, 32.5M)   gates..scan
    //   Dr   [32.5M, 40.9M)   gates..scan
    //   st   [40.9M, 49.3M)   scan..post
    //   h1   [49.3M, 59.8M)   post..mlp1 (bf16)
    //   h2b  [1M, 34.6M)      mlp1..proj_out (over hf/Ag/Dr-head: dead)
    //   Ub   [34.6M, 68.2M)   gemm_u..proj_out (over Dr-tail/st/h1: dead)
    char* ws = (char*)d_ws;
    u16*   wbf = (u16*)(ws + 0);
    u16*   w1b = wbf;
    u16*   w2b = wbf + 65536;
    u16*   wpb = wbf + 131072;
    u16*   owb = wbf + 196608;
    float* hf  = (float*)(ws + 1048576);
    float* raw = (float*)(ws + 24117248);
    float* Ag  = (float*)(ws + 24117248);
    float* Dr  = (float*)(ws + 32505856);
    float* st  = (float*)(ws + 40894464);
    u16*   h1  = (u16*)(ws + 49283072);
    u16*   h2b = (u16*)(ws + 1048576);
    u16*   Ub  = (u16*)(ws + 34603008);
    float* out = (float*)d_out;

    k_prep <<<1792, 256, 0, stream>>>(r_w1, r_w2, r_proj, out_w, wbf);
    k_hash <<<256, 256, 0, stream>>>(chars, table0, table1, table2, table3, cond_w, raw);
    k_feat <<<256, 256, 0, stream>>>(chars, byte_embed, raw, conv_w, conv_b, hf);
    k_gates<<<1024, 256, 0, stream>>>(hf, gate_w, gate_b, inpr_w, inpr_b, Ag, Dr);
    k_scan_par<<<1024, 64, 0, stream>>>(Ag, Dr, st);
    k_post <<<256, 256, 0, stream>>>(st, hf, outpr_w, outpr_b, scan_ln_w, scan_ln_b, h1);
    k_mlp1 <<<1024, 256, 0, stream>>>(h1, inp_w, inp_b, h2b);
    k_gemm_u  <<<dim3(1024, 2), 256, 0, stream>>>(h2b, w1b, w2b, Ub);
    k_proj_out<<<1024, 256, 0, stream>>>(Ub, wpb, h2b, r_ln_w, r_ln_b, owb, out_b, out);
}

// Round 5
// 499.242 us; speedup vs baseline: 7.1753x; 1.0471x over previous
//
#include <hip/hip_runtime.h>

#define BB 32
#define TT 2048
#define SS 32
#define DD 80
#define HH 256
#define VV 1024
#define EBD 64

typedef unsigned short u16;
typedef __attribute__((ext_vector_type(8))) __bf16 bf16x8;
typedef __attribute__((ext_vector_type(4))) float f32x4;

#define MFMA(a, b, c) __builtin_amdgcn_mfma_f32_16x16x32_bf16(a, b, c, 0, 0, 0)

__device__ inline u16 f2bu(float f) {
    unsigned u = __float_as_uint(f);
    return (u16)((u + 0x7FFFu + ((u >> 16) & 1u)) >> 16);
}
__device__ inline __bf16 f2b(float f) {
    u16 r = f2bu(f);
    return __builtin_bit_cast(__bf16, r);
}
__device__ inline float b2f(u16 h) { return __uint_as_float(((unsigned)h) << 16); }

// A/B fragment (16 rows x 32 k) from bf16 row-major [.][256]
__device__ inline bf16x8 ldfrag(const u16* base, int row, int k0, int lane) {
    return *(const bf16x8*)(base + (size_t)row * 256 + k0 + ((lane >> 4) << 3));
}

// ---------------------------------------------------------------------------
// Kernel P: convert GEMM weights f32 -> bf16 once per launch
// ---------------------------------------------------------------------------
__global__ __launch_bounds__(256) void k_prep(const float* __restrict__ w1,
                                              const float* __restrict__ w2,
                                              const float* __restrict__ wp,
                                              const float* __restrict__ ow,
                                              u16* __restrict__ wbf) {
    int i = blockIdx.x * 256 + threadIdx.x;
    if (i >= 458752) return;
    float v;
    if (i < 65536) v = w1[i];
    else if (i < 131072) v = w2[i - 65536];
    else if (i < 196608) v = wp[i - 131072];
    else v = ow[i - 196608];
    wbf[i] = f2bu(v);
}

// ---------------------------------------------------------------------------
// Kernel A: polynomial rolling hashes + table gathers + conditioned long keys
// ---------------------------------------------------------------------------
__global__ __launch_bounds__(256) void k_hash(const int* __restrict__ tok,
                                              const float* __restrict__ t0,
                                              const float* __restrict__ t1,
                                              const float* __restrict__ t2,
                                              const float* __restrict__ t3,
                                              const float* __restrict__ cond_w,
                                              float* __restrict__ raw) {
    int idx = blockIdx.x * 256 + threadIdx.x;
    if (idx >= BB * TT) return;
    int b = idx / TT, t = idx % TT;
    const int* tr = tok + b * TT;

    unsigned long long tv[8];
#pragma unroll
    for (int i = 0; i < 8; i++) {
        int ts = t - 1 - i;
        tv[i] = (ts >= 0) ? (unsigned long long)(unsigned)tr[ts] : 0ull;
    }
    const unsigned long long P[8] = {2654435761ull, 2246822519ull, 3266489917ull,
                                     2028178513ull, 1220703125ull, 1610612741ull,
                                     805306457ull, 402653189ull};
    unsigned long long x = 0ull;
    x ^= tv[0] * P[0]; unsigned long long k0 = x % 2000000ull;
    x ^= tv[1] * P[1]; unsigned long long k1 = x % 2000000ull;
    x ^= tv[2] * P[2]; x ^= tv[3] * P[3]; unsigned long long k2 = x % 2000000ull;
    x ^= tv[4] * P[4]; x ^= tv[5] * P[5];
    x ^= tv[6] * P[6]; x ^= tv[7] * P[7]; unsigned long long k3 = x % 2000000ull;

    float f0 = t0[k0 * 2], f1 = t0[k0 * 2 + 1];
    float f2 = t1[k1 * 2], f3 = t1[k1 * 2 + 1];

    unsigned long long ck = 0ull;
#pragma unroll
    for (int j = 0; j < 8; j++) {
        float lg = f0 * cond_w[j * 4 + 0] + f1 * cond_w[j * 4 + 1] +
                   f2 * cond_w[j * 4 + 2] + f3 * cond_w[j * 4 + 3];
        if (lg > 0.f) ck ^= P[j];
    }
    unsigned long long lk2 = (k2 ^ ck) % 2000000ull;
    unsigned long long lk3 = (k3 ^ ck) % 2000000ull;

    float* o = raw + (size_t)idx * 8;
    o[0] = f0; o[1] = f1; o[2] = f2; o[3] = f3;
    o[4] = t2[lk2 * 2]; o[5] = t2[lk2 * 2 + 1];
    o[6] = t3[lk3 * 2]; o[7] = t3[lk3 * 2 + 1];
}

// ---------------------------------------------------------------------------
// Kernel B: causal depthwise conv + silu, assemble h[b,t,80]
// ---------------------------------------------------------------------------
__global__ __launch_bounds__(256) void k_feat(const int* __restrict__ tok,
                                              const float* __restrict__ be,
                                              const float* __restrict__ raw,
                                              const float* __restrict__ conv_w,
                                              const float* __restrict__ conv_b,
                                              float* __restrict__ hf) {
    int idx = blockIdx.x * 256 + threadIdx.x;
    if (idx >= BB * TT) return;
    int b = idx / TT, t = idx % TT;
    const int* tr = tok + b * TT;
    float* o = hf + (size_t)idx * DD;

    int tk = tr[t];
    const float* ber = be + (size_t)tk * EBD;
#pragma unroll 8
    for (int d = 0; d < EBD; d++) o[d] = ber[d];

#pragma unroll
    for (int c = 0; c < 8; c++) {
        float acc = conv_b[c];
#pragma unroll
        for (int k = 0; k < 8; k++) {
            int ts = t - 7 + k;
            if (ts >= 0) acc += conv_w[c * 8 + k] * raw[((size_t)(b * TT + ts)) * 8 + c];
        }
        o[64 + c] = acc / (1.f + expf(-acc));
    }

#pragma unroll
    for (int k = 1; k <= 8; k++) {
        float m = (t >= k && tr[t] == tr[t - k]) ? 1.f : 0.f;
        o[71 + k] = m;
    }
}

// ---------------------------------------------------------------------------
// Kernel C: scan gates
// ---------------------------------------------------------------------------
__global__ __launch_bounds__(256) void k_gates(const float* __restrict__ hf,
                                               const float* __restrict__ gw,
                                               const float* __restrict__ gb,
                                               const float* __restrict__ iw,
                                               const float* __restrict__ ib,
                                               float* __restrict__ Ag,
                                               float* __restrict__ Dr) {
    __shared__ float xs[64][DD];
    int blk = blockIdx.x;
    int b = blk >> 5;
    int t0 = (blk & 31) << 6;
    const float* src = hf + ((size_t)(b * TT + t0)) * DD;
    for (int i = threadIdx.x; i < 64 * DD; i += 256) xs[i / DD][i % DD] = src[i];
    __syncthreads();

    for (int p = threadIdx.x; p < 64 * SS; p += 256) {
        int s = p & 31, tt = p >> 5;
        float ga = gb[s], ia = ib[s];
        for (int d = 0; d < DD; d++) {
            float xv = xs[tt][d];
            ga += xv * gw[s * DD + d];
            ia += xv * iw[s * DD + d];
        }
        float g = 1.f / (1.f + expf(-ga));
        float drv = (1.f - g) * ia;
        size_t oo = ((size_t)(b * SS + s)) * TT + t0 + tt;
        Ag[oo] = g;
        Dr[oo] = drv;
    }
}

// ---------------------------------------------------------------------------
// Kernel D: parallel chunked scan (wave-scan of per-chunk linear maps)
// ---------------------------------------------------------------------------
__global__ __launch_bounds__(64) void k_scan_par(const float* __restrict__ Ag,
                                                 const float* __restrict__ Dr,
                                                 float* __restrict__ st) {
    int bs = blockIdx.x;
    int b = bs >> 5, s = bs & 31;
    int c = threadIdx.x;
    const float* ar = Ag + (size_t)bs * TT + c * 32;
    const float* dr = Dr + (size_t)bs * TT + c * 32;

    float ca[32], cw[32];
    float lacc = 0.f, wacc = 0.f;
#pragma unroll
    for (int k = 0; k < 32; k += 4) {
        f32x4 av = *(const f32x4*)(ar + k);
        f32x4 dv = *(const f32x4*)(dr + k);
#pragma unroll
        for (int j = 0; j < 4; j++) {
            lacc += logf(fmaxf(av[j], 1e-6f));
            float cav = expf(lacc);
            ca[k + j] = cav;
            wacc += dv[j] / fmaxf(cav, 1e-8f);
            cw[k + j] = wacc;
        }
    }

    float A = ca[31];
    float Bc = ca[31] * wacc;
    for (int off = 1; off < 64; off <<= 1) {
        float Ap = __shfl_up(A, off, 64);
        float Bp = __shfl_up(Bc, off, 64);
        if (c >= off) {
            Bc = A * Bp + Bc;
            A = A * Ap;
        }
    }
    float h0 = __shfl_up(Bc, 1, 64);
    if (c == 0) h0 = 0.f;

    float* op = st + ((size_t)(b * TT + c * 32)) * SS + s;
#pragma unroll
    for (int k = 0; k < 32; k++)
        op[(size_t)k * SS] = ca[k] * (h0 + cw[k]);
}

// ---------------------------------------------------------------------------
// Kernel E: y = states @ outpr_w^T + ob ; h1 = LN(hf + y)  (bf16 out)
// ---------------------------------------------------------------------------
__global__ __launch_bounds__(256) void k_post(const float* __restrict__ st,
                                              const float* __restrict__ hf,
                                              const float* __restrict__ ow,
                                              const float* __restrict__ ob,
                                              const float* __restrict__ lnw,
                                              const float* __restrict__ lnb,
                                              u16* __restrict__ h1) {
    int idx = blockIdx.x * 256 + threadIdx.x;
    if (idx >= BB * TT) return;
    const float* sp = st + (size_t)idx * SS;
    float sv[SS];
#pragma unroll
    for (int i = 0; i < SS; i++) sv[i] = sp[i];
    const float* x = hf + (size_t)idx * DD;

    float s1 = 0.f, s2 = 0.f;
    for (int d = 0; d < DD; d++) {
        float acc = ob[d];
#pragma unroll
        for (int i = 0; i < SS; i++) acc += sv[i] * ow[d * SS + i];
        float v = acc + x[d];
        s1 += v; s2 += v * v;
    }
    float m = s1 * (1.f / DD);
    float var = s2 * (1.f / DD) - m * m;
    float rs = rsqrtf(var + 1e-5f);
    for (int d = 0; d < DD; d++) {
        float acc = ob[d];
#pragma unroll
        for (int i = 0; i < SS; i++) acc += sv[i] * ow[d * SS + i];
        float v = acc + x[d];
        h1[(size_t)idx * DD + d] = f2bu((v - m) * rs * lnw[d] + lnb[d]);
    }
}

// ---------------------------------------------------------------------------
// Kernel F: h2 = silu(h1 @ inp_w^T + inp_b), 80 -> 256, bf16 in/out
// ---------------------------------------------------------------------------
__global__ __launch_bounds__(256) void k_mlp1(const u16* __restrict__ h1,
                                              const float* __restrict__ w,
                                              const float* __restrict__ bias,
                                              u16* __restrict__ h2) {
    __shared__ float xs[64][DD];
    int blk = blockIdx.x;
    int b = blk >> 5;
    int t0 = (blk & 31) << 6;
    const u16* src = h1 + ((size_t)(b * TT + t0)) * DD;
    for (int i = threadIdx.x; i < 64 * DD; i += 256) xs[i / DD][i % DD] = b2f(src[i]);
    __syncthreads();

    int j = threadIdx.x;
    float bj = bias[j];
    for (int tt0 = 0; tt0 < 64; tt0 += 16) {
        float acc[16];
#pragma unroll
        for (int r = 0; r < 16; r++) acc[r] = bj;
        for (int d = 0; d < DD; d++) {
            float wv = w[j * DD + d];
#pragma unroll
            for (int r = 0; r < 16; r++) acc[r] += xs[tt0 + r][d] * wv;
        }
#pragma unroll
        for (int r = 0; r < 16; r++) {
            float v = acc[r];
            h2[((size_t)(b * TT + t0 + tt0 + r)) * HH + j] = f2bu(v / (1.f + expf(-v)));
        }
    }
}

// ---------------------------------------------------------------------------
// Kernel G1 (MFMA): U = silu(X@w1^T) * (X@w2^T), bf16 everywhere, K=256
// ---------------------------------------------------------------------------
__global__ __launch_bounds__(256) void k_gemm_u(const u16* __restrict__ x,
                                                const u16* __restrict__ w1,
                                                const u16* __restrict__ w2,
                                                u16* __restrict__ U) {
    int lane = threadIdx.x & 63, wv = threadIdx.x >> 6;
    int r0 = blockIdx.x * 64;
    int c0 = blockIdx.y * 128 + wv * 32;
    f32x4 a1[4][2] = {}, a2[4][2] = {};
    for (int ks = 0; ks < 8; ks++) {
        int k0 = ks * 32;
        bf16x8 a[4];
#pragma unroll
        for (int mi = 0; mi < 4; mi++) a[mi] = ldfrag(x, r0 + mi * 16 + (lane & 15), k0, lane);
#pragma unroll
        for (int ni = 0; ni < 2; ni++) {
            bf16x8 b1 = ldfrag(w1, c0 + ni * 16 + (lane & 15), k0, lane);
            bf16x8 b2 = ldfrag(w2, c0 + ni * 16 + (lane & 15), k0, lane);
#pragma unroll
            for (int mi = 0; mi < 4; mi++) {
                a1[mi][ni] = MFMA(a[mi], b1, a1[mi][ni]);
                a2[mi][ni] = MFMA(a[mi], b2, a2[mi][ni]);
            }
        }
    }
    int g = lane >> 4, cl = lane & 15;
#pragma unroll
    for (int mi = 0; mi < 4; mi++)
#pragma unroll
        for (int ni = 0; ni < 2; ni++)
#pragma unroll
            for (int r = 0; r < 4; r++) {
                float v1 = a1[mi][ni][r], v2 = a2[mi][ni][r];
                float u = v1 / (1.f + expf(-v1)) * v2;
                U[(size_t)(r0 + mi * 16 + g * 4 + r) * 256 + c0 + ni * 16 + cl] = f2bu(u);
            }
}

// ---------------------------------------------------------------------------
// Kernel G2 (MFMA): hh = U@wp^T; V = hh + X; h3 = LN(V), bf16 out.
// h3 aliases U (each block reads only its own rows, then writes them).
// ---------------------------------------------------------------------------
__global__ __launch_bounds__(256) void k_gemm_proj(const u16* __restrict__ U,
                                                   const u16* __restrict__ wp,
                                                   const u16* __restrict__ x,
                                                   const float* __restrict__ lnw,
                                                   const float* __restrict__ lnb,
                                                   u16* __restrict__ h3) {
    __shared__ float redS[64][4], redQ[64][4];
    int lane = threadIdx.x & 63, wv = threadIdx.x >> 6;
    int r0 = blockIdx.x * 64;
    int c0 = wv * 64;
    f32x4 acc[4][4] = {};
    for (int ks = 0; ks < 8; ks++) {
        int k0 = ks * 32;
        bf16x8 a[4];
#pragma unroll
        for (int mi = 0; mi < 4; mi++) a[mi] = ldfrag(U, r0 + mi * 16 + (lane & 15), k0, lane);
#pragma unroll
        for (int ni = 0; ni < 4; ni++) {
            bf16x8 b = ldfrag(wp, c0 + ni * 16 + (lane & 15), k0, lane);
#pragma unroll
            for (int mi = 0; mi < 4; mi++) acc[mi][ni] = MFMA(a[mi], b, acc[mi][ni]);
        }
    }
    int g = lane >> 4, cl = lane & 15;
#pragma unroll
    for (int mi = 0; mi < 4; mi++)
#pragma unroll
        for (int r = 0; r < 4; r++) {
            float s = 0.f, q = 0.f;
            int row = mi * 16 + g * 4 + r;
#pragma unroll
            for (int ni = 0; ni < 4; ni++) {
                int col = c0 + ni * 16 + cl;
                float v = acc[mi][ni][r] + b2f(x[(size_t)(r0 + row) * 256 + col]);
                acc[mi][ni][r] = v;
                s += v; q += v * v;
            }
            for (int m = 1; m < 16; m <<= 1) {
                s += __shfl_xor(s, m, 64);
                q += __shfl_xor(q, m, 64);
            }
            if (cl == 0) { redS[row][wv] = s; redQ[row][wv] = q; }
        }
    __syncthreads();

    float lw[4], lb[4];
#pragma unroll
    for (int ni = 0; ni < 4; ni++) {
        lw[ni] = lnw[c0 + ni * 16 + cl];
        lb[ni] = lnb[c0 + ni * 16 + cl];
    }
#pragma unroll
    for (int mi = 0; mi < 4; mi++)
#pragma unroll
        for (int r = 0; r < 4; r++) {
            int row = mi * 16 + g * 4 + r;
            float S = redS[row][0] + redS[row][1] + redS[row][2] + redS[row][3];
            float Q = redQ[row][0] + redQ[row][1] + redQ[row][2] + redQ[row][3];
            float m = S * (1.f / 256.f);
            float rs = rsqrtf(Q * (1.f / 256.f) - m * m + 1e-5f);
#pragma unroll
            for (int ni = 0; ni < 4; ni++) {
                float y = (acc[mi][ni][r] - m) * rs * lw[ni] + lb[ni];
                h3[(size_t)(r0 + row) * 256 + c0 + ni * 16 + cl] = f2bu(y);
            }
        }
}

// ---------------------------------------------------------------------------
// Kernel H (MFMA): out = h3 @ out_w^T + out_b. Barrier-free, no LDS.
// grid (1024, 4); wave = 64 rows x 64 cols; explicit 1-deep prefetch of
// A and B fragments so the compiler overlaps L2 latency with MFMA.
// The 4 col-group blocks of a row-tile share bx%8 -> same XCD L2 for A.
// ---------------------------------------------------------------------------
__global__ __launch_bounds__(256) void k_out2(const u16* __restrict__ h3,
                                              const u16* __restrict__ ow,
                                              const float* __restrict__ bias,
                                              float* __restrict__ out) {
    int lane = threadIdx.x & 63, wv = threadIdx.x >> 6;
    int r0 = blockIdx.x * 64;
    int c0 = blockIdx.y * 256 + wv * 64;
    int rl = lane & 15;

    f32x4 acc[4][4] = {};
    bf16x8 a[4], b[4];
#pragma unroll
    for (int mi = 0; mi < 4; mi++) a[mi] = ldfrag(h3, r0 + mi * 16 + rl, 0, lane);
#pragma unroll
    for (int ni = 0; ni < 4; ni++) b[ni] = ldfrag(ow, c0 + ni * 16 + rl, 0, lane);

#pragma unroll
    for (int ks = 0; ks < 8; ks++) {
        bf16x8 an[4], bn[4];
        if (ks < 7) {
#pragma unroll
            for (int mi = 0; mi < 4; mi++) an[mi] = ldfrag(h3, r0 + mi * 16 + rl, (ks + 1) * 32, lane);
#pragma unroll
            for (int ni = 0; ni < 4; ni++) bn[ni] = ldfrag(ow, c0 + ni * 16 + rl, (ks + 1) * 32, lane);
        }
#pragma unroll
        for (int ni = 0; ni < 4; ni++)
#pragma unroll
            for (int mi = 0; mi < 4; mi++) acc[mi][ni] = MFMA(a[mi], b[ni], acc[mi][ni]);
        if (ks < 7) {
#pragma unroll
            for (int mi = 0; mi < 4; mi++) a[mi] = an[mi];
#pragma unroll
            for (int ni = 0; ni < 4; ni++) b[ni] = bn[ni];
        }
    }

    int g = lane >> 4, cl = lane & 15;
#pragma unroll
    for (int ni = 0; ni < 4; ni++) {
        float bv = bias[c0 + ni * 16 + cl];
#pragma unroll
        for (int mi = 0; mi < 4; mi++)
#pragma unroll
            for (int r = 0; r < 4; r++)
                out[(size_t)(r0 + mi * 16 + g * 4 + r) * VV + c0 + ni * 16 + cl] =
                    acc[mi][ni][r] + bv;
    }
}

// ---------------------------------------------------------------------------
extern "C" void kernel_launch(void* const* d_in, const int* in_sizes, int n_in,
                              void* d_out, int out_size, void* d_ws, size_t ws_size,
                              hipStream_t stream) {
    const int* chars        = (const int*)d_in[0];
    const float* byte_embed = (const float*)d_in[1];
    const float* table0     = (const float*)d_in[2];
    const float* table1     = (const float*)d_in[3];
    const float* table2     = (const float*)d_in[4];
    const float* table3     = (const float*)d_in[5];
    const float* cond_w     = (const float*)d_in[6];
    const float* conv_w     = (const float*)d_in[7];
    const float* conv_b     = (const float*)d_in[8];
    const float* gate_w     = (const float*)d_in[9];
    const float* gate_b     = (const float*)d_in[10];
    const float* inpr_w     = (const float*)d_in[11];
    const float* inpr_b     = (const float*)d_in[12];
    const float* outpr_w    = (const float*)d_in[13];
    const float* outpr_b    = (const float*)d_in[14];
    const float* scan_ln_w  = (const float*)d_in[15];
    const float* scan_ln_b  = (const float*)d_in[16];
    const float* inp_w      = (const float*)d_in[17];
    const float* inp_b      = (const float*)d_in[18];
    const float* r_w1       = (const float*)d_in[19];
    const float* r_w2       = (const float*)d_in[20];
    const float* r_proj     = (const float*)d_in[21];
    const float* r_ln_w     = (const float*)d_in[22];
    const float* r_ln_b     = (const float*)d_in[23];
    const float* out_w      = (const float*)d_in[24];
    const float* out_b      = (const float*)d_in[25];

    // ws layout with lifetimes (peak 68.2 MB):
    //   wbf  [0, 0.9M)        prep..end (persistent bf16 weights)
    //   hf   [1M, 24.1M)      feat..post
    //   raw  [24.1M, 26.2M)   hash..feat
    //   Ag   [24.1M, 32.5M)   gates..scan
    //   Dr   [32.5M, 40.9M)   gates..scan
    //   st   [40.9M, 49.3M)   scan..post
    //   h1   [49.3M, 59.8M)   post..mlp1 (bf16)
    //   h2b  [1M, 34.6M)      mlp1..gemm_proj (over hf/Ag/Dr-head: dead)
    //   Ub   [34.6M, 68.2M)   gemm_u..gemm_proj (over Dr-tail/st/h1: dead)
    //   h3b  aliases Ub       gemm_proj..out2 (row-for-row, safe)
    char* ws = (char*)d_ws;
    u16*   wbf = (u16*)(ws + 0);
    u16*   w1b = wbf;
    u16*   w2b = wbf + 65536;
    u16*   wpb = wbf + 131072;
    u16*   owb = wbf + 196608;
    float* hf  = (float*)(ws + 1048576);
    float* raw = (float*)(ws + 24117248);
    float* Ag  = (float*)(ws + 24117248);
    float* Dr  = (float*)(ws + 32505856);
    float* st  = (float*)(ws + 40894464);
    u16*   h1  = (u16*)(ws + 49283072);
    u16*   h2b = (u16*)(ws + 1048576);
    u16*   Ub  = (u16*)(ws + 34603008);
    u16*   h3b = (u16*)(ws + 34603008);
    float* out = (float*)d_out;

    k_prep <<<1792, 256, 0, stream>>>(r_w1, r_w2, r_proj, out_w, wbf);
    k_hash <<<256, 256, 0, stream>>>(chars, table0, table1, table2, table3, cond_w, raw);
    k_feat <<<256, 256, 0, stream>>>(chars, byte_embed, raw, conv_w, conv_b, hf);
    k_gates<<<1024, 256, 0, stream>>>(hf, gate_w, gate_b, inpr_w, inpr_b, Ag, Dr);
    k_scan_par<<<1024, 64, 0, stream>>>(Ag, Dr, st);
    k_post <<<256, 256, 0, stream>>>(st, hf, outpr_w, outpr_b, scan_ln_w, scan_ln_b, h1);
    k_mlp1 <<<1024, 256, 0, stream>>>(h1, inp_w, inp_b, h2b);
    k_gemm_u   <<<dim3(1024, 2), 256, 0, stream>>>(h2b, w1b, w2b, Ub);
    k_gemm_proj<<<1024, 256, 0, stream>>>(Ub, wpb, h2b, r_ln_w, r_ln_b, h3b);
    k_out2     <<<dim3(1024, 4), 256, 0, stream>>>(h3b, owb, out_b, out);
}

// Round 6
// 397.366 us; speedup vs baseline: 9.0149x; 1.2564x over previous
//
#include <hip/hip_runtime.h>

#define BB 32
#define TT 2048
#define SS 32
#define DD 80
#define HH 256
#define VV 1024
#define EBD 64

typedef unsigned short u16;
typedef __attribute__((ext_vector_type(8))) __bf16 bf16x8;
typedef __attribute__((ext_vector_type(4))) float f32x4;

#define MFMA(a, b, c) __builtin_amdgcn_mfma_f32_16x16x32_bf16(a, b, c, 0, 0, 0)

__device__ inline u16 f2bu(float f) {
    unsigned u = __float_as_uint(f);
    return (u16)((u + 0x7FFFu + ((u >> 16) & 1u)) >> 16);
}
__device__ inline __bf16 f2b(float f) {
    u16 r = f2bu(f);
    return __builtin_bit_cast(__bf16, r);
}
__device__ inline float b2f(u16 h) { return __uint_as_float(((unsigned)h) << 16); }

// A/B fragment (16 rows x 32 k) from bf16 row-major [.][256]
__device__ inline bf16x8 ldfrag(const u16* base, int row, int k0, int lane) {
    return *(const bf16x8*)(base + (size_t)row * 256 + k0 + ((lane >> 4) << 3));
}
// same from row-major [.][96]
__device__ inline bf16x8 ldfrag96(const u16* base, int row, int k0, int lane) {
    return *(const bf16x8*)(base + (size_t)row * 96 + k0 + ((lane >> 4) << 3));
}

// ---------------------------------------------------------------------------
// Kernel P: convert GEMM weights f32 -> bf16 once per launch.
// wbf: r_w1[0,64K) r_w2[64K,128K) r_proj[128K,192K) out_w[192K,448K)
//      inp_w padded [256][96] at [448K, 472K)
// ---------------------------------------------------------------------------
__global__ __launch_bounds__(256) void k_prep(const float* __restrict__ w1,
                                              const float* __restrict__ w2,
                                              const float* __restrict__ wp,
                                              const float* __restrict__ ow,
                                              const float* __restrict__ iw,
                                              u16* __restrict__ wbf) {
    int i = blockIdx.x * 256 + threadIdx.x;
    if (i >= 483328) return;
    float v;
    if (i < 65536) v = w1[i];
    else if (i < 131072) v = w2[i - 65536];
    else if (i < 196608) v = wp[i - 131072];
    else if (i < 458752) v = ow[i - 196608];
    else {
        int j = i - 458752;
        int row = j / 96, col = j % 96;
        v = (col < 80) ? iw[row * 80 + col] : 0.f;
    }
    wbf[i] = f2bu(v);
}

// ---------------------------------------------------------------------------
// Kernel A: polynomial rolling hashes + table gathers + conditioned long keys
// ---------------------------------------------------------------------------
__global__ __launch_bounds__(256) void k_hash(const int* __restrict__ tok,
                                              const float* __restrict__ t0,
                                              const float* __restrict__ t1,
                                              const float* __restrict__ t2,
                                              const float* __restrict__ t3,
                                              const float* __restrict__ cond_w,
                                              float* __restrict__ raw) {
    int idx = blockIdx.x * 256 + threadIdx.x;
    if (idx >= BB * TT) return;
    int b = idx / TT, t = idx % TT;
    const int* tr = tok + b * TT;

    unsigned long long tv[8];
#pragma unroll
    for (int i = 0; i < 8; i++) {
        int ts = t - 1 - i;
        tv[i] = (ts >= 0) ? (unsigned long long)(unsigned)tr[ts] : 0ull;
    }
    const unsigned long long P[8] = {2654435761ull, 2246822519ull, 3266489917ull,
                                     2028178513ull, 1220703125ull, 1610612741ull,
                                     805306457ull, 402653189ull};
    unsigned long long x = 0ull;
    x ^= tv[0] * P[0]; unsigned long long k0 = x % 2000000ull;
    x ^= tv[1] * P[1]; unsigned long long k1 = x % 2000000ull;
    x ^= tv[2] * P[2]; x ^= tv[3] * P[3]; unsigned long long k2 = x % 2000000ull;
    x ^= tv[4] * P[4]; x ^= tv[5] * P[5];
    x ^= tv[6] * P[6]; x ^= tv[7] * P[7]; unsigned long long k3 = x % 2000000ull;

    float f0 = t0[k0 * 2], f1 = t0[k0 * 2 + 1];
    float f2 = t1[k1 * 2], f3 = t1[k1 * 2 + 1];

    unsigned long long ck = 0ull;
#pragma unroll
    for (int j = 0; j < 8; j++) {
        float lg = f0 * cond_w[j * 4 + 0] + f1 * cond_w[j * 4 + 1] +
                   f2 * cond_w[j * 4 + 2] + f3 * cond_w[j * 4 + 3];
        if (lg > 0.f) ck ^= P[j];
    }
    unsigned long long lk2 = (k2 ^ ck) % 2000000ull;
    unsigned long long lk3 = (k3 ^ ck) % 2000000ull;

    float* o = raw + (size_t)idx * 8;
    o[0] = f0; o[1] = f1; o[2] = f2; o[3] = f3;
    o[4] = t2[lk2 * 2]; o[5] = t2[lk2 * 2 + 1];
    o[6] = t3[lk3 * 2]; o[7] = t3[lk3 * 2 + 1];
}

// ---------------------------------------------------------------------------
// Kernel B: causal depthwise conv + silu, assemble h[b,t,80]
// ---------------------------------------------------------------------------
__global__ __launch_bounds__(256) void k_feat(const int* __restrict__ tok,
                                              const float* __restrict__ be,
                                              const float* __restrict__ raw,
                                              const float* __restrict__ conv_w,
                                              const float* __restrict__ conv_b,
                                              float* __restrict__ hf) {
    int idx = blockIdx.x * 256 + threadIdx.x;
    if (idx >= BB * TT) return;
    int b = idx / TT, t = idx % TT;
    const int* tr = tok + b * TT;
    float* o = hf + (size_t)idx * DD;

    int tk = tr[t];
    const float* ber = be + (size_t)tk * EBD;
#pragma unroll 8
    for (int d = 0; d < EBD; d++) o[d] = ber[d];

#pragma unroll
    for (int c = 0; c < 8; c++) {
        float acc = conv_b[c];
#pragma unroll
        for (int k = 0; k < 8; k++) {
            int ts = t - 7 + k;
            if (ts >= 0) acc += conv_w[c * 8 + k] * raw[((size_t)(b * TT + ts)) * 8 + c];
        }
        o[64 + c] = acc / (1.f + expf(-acc));
    }

#pragma unroll
    for (int k = 1; k <= 8; k++) {
        float m = (t >= k && tr[t] == tr[t - k]) ? 1.f : 0.f;
        o[71 + k] = m;
    }
}

// ---------------------------------------------------------------------------
// Kernel C: scan gates
// ---------------------------------------------------------------------------
__global__ __launch_bounds__(256) void k_gates(const float* __restrict__ hf,
                                               const float* __restrict__ gw,
                                               const float* __restrict__ gb,
                                               const float* __restrict__ iw,
                                               const float* __restrict__ ib,
                                               float* __restrict__ Ag,
                                               float* __restrict__ Dr) {
    __shared__ float xs[64][DD];
    int blk = blockIdx.x;
    int b = blk >> 5;
    int t0 = (blk & 31) << 6;
    const float* src = hf + ((size_t)(b * TT + t0)) * DD;
    for (int i = threadIdx.x; i < 64 * DD; i += 256) xs[i / DD][i % DD] = src[i];
    __syncthreads();

    for (int p = threadIdx.x; p < 64 * SS; p += 256) {
        int s = p & 31, tt = p >> 5;
        float ga = gb[s], ia = ib[s];
        for (int d = 0; d < DD; d++) {
            float xv = xs[tt][d];
            ga += xv * gw[s * DD + d];
            ia += xv * iw[s * DD + d];
        }
        float g = 1.f / (1.f + expf(-ga));
        float drv = (1.f - g) * ia;
        size_t oo = ((size_t)(b * SS + s)) * TT + t0 + tt;
        Ag[oo] = g;
        Dr[oo] = drv;
    }
}

// ---------------------------------------------------------------------------
// Kernel D: parallel chunked scan (wave-scan of per-chunk linear maps)
// ---------------------------------------------------------------------------
__global__ __launch_bounds__(64) void k_scan_par(const float* __restrict__ Ag,
                                                 const float* __restrict__ Dr,
                                                 float* __restrict__ st) {
    int bs = blockIdx.x;
    int b = bs >> 5, s = bs & 31;
    int c = threadIdx.x;
    const float* ar = Ag + (size_t)bs * TT + c * 32;
    const float* dr = Dr + (size_t)bs * TT + c * 32;

    float ca[32], cw[32];
    float lacc = 0.f, wacc = 0.f;
#pragma unroll
    for (int k = 0; k < 32; k += 4) {
        f32x4 av = *(const f32x4*)(ar + k);
        f32x4 dv = *(const f32x4*)(dr + k);
#pragma unroll
        for (int j = 0; j < 4; j++) {
            lacc += logf(fmaxf(av[j], 1e-6f));
            float cav = expf(lacc);
            ca[k + j] = cav;
            wacc += dv[j] / fmaxf(cav, 1e-8f);
            cw[k + j] = wacc;
        }
    }

    float A = ca[31];
    float Bc = ca[31] * wacc;
    for (int off = 1; off < 64; off <<= 1) {
        float Ap = __shfl_up(A, off, 64);
        float Bp = __shfl_up(Bc, off, 64);
        if (c >= off) {
            Bc = A * Bp + Bc;
            A = A * Ap;
        }
    }
    float h0 = __shfl_up(Bc, 1, 64);
    if (c == 0) h0 = 0.f;

    float* op = st + ((size_t)(b * TT + c * 32)) * SS + s;
#pragma unroll
    for (int k = 0; k < 32; k++)
        op[(size_t)k * SS] = ca[k] * (h0 + cw[k]);
}

// ---------------------------------------------------------------------------
// Kernel E: y = states @ outpr_w^T + ob ; h1 = LN(hf + y)
// writes h1 padded to [.][96] bf16 (cols 80..95 = 0) for the MFMA mlp1.
// ---------------------------------------------------------------------------
__global__ __launch_bounds__(256) void k_post(const float* __restrict__ st,
                                              const float* __restrict__ hf,
                                              const float* __restrict__ ow,
                                              const float* __restrict__ ob,
                                              const float* __restrict__ lnw,
                                              const float* __restrict__ lnb,
                                              u16* __restrict__ h1p) {
    int idx = blockIdx.x * 256 + threadIdx.x;
    if (idx >= BB * TT) return;
    const float* sp = st + (size_t)idx * SS;
    float sv[SS];
#pragma unroll
    for (int i = 0; i < SS; i++) sv[i] = sp[i];
    const float* x = hf + (size_t)idx * DD;

    float s1 = 0.f, s2 = 0.f;
    for (int d = 0; d < DD; d++) {
        float acc = ob[d];
#pragma unroll
        for (int i = 0; i < SS; i++) acc += sv[i] * ow[d * SS + i];
        float v = acc + x[d];
        s1 += v; s2 += v * v;
    }
    float m = s1 * (1.f / DD);
    float var = s2 * (1.f / DD) - m * m;
    float rs = rsqrtf(var + 1e-5f);
    u16* o = h1p + (size_t)idx * 96;
    for (int d = 0; d < DD; d++) {
        float acc = ob[d];
#pragma unroll
        for (int i = 0; i < SS; i++) acc += sv[i] * ow[d * SS + i];
        float v = acc + x[d];
        o[d] = f2bu((v - m) * rs * lnw[d] + lnb[d]);
    }
    *(f32x4*)(o + 80) = f32x4{0.f, 0.f, 0.f, 0.f};
    *(f32x4*)(o + 88) = f32x4{0.f, 0.f, 0.f, 0.f};
}

// ---------------------------------------------------------------------------
// Kernel F (MFMA): h2 = silu(h1p @ inp_w_b^T + inp_b), K=96 (3 k-steps)
// ---------------------------------------------------------------------------
__global__ __launch_bounds__(256) void k_mlp1m(const u16* __restrict__ h1p,
                                               const u16* __restrict__ wb,
                                               const float* __restrict__ bias,
                                               u16* __restrict__ h2) {
    int lane = threadIdx.x & 63, wv = threadIdx.x >> 6;
    int r0 = blockIdx.x * 64;
    int c0 = wv * 64;
    f32x4 acc[4][4] = {};
#pragma unroll
    for (int ks = 0; ks < 3; ks++) {
        int k0 = ks * 32;
        bf16x8 a[4];
#pragma unroll
        for (int mi = 0; mi < 4; mi++) a[mi] = ldfrag96(h1p, r0 + mi * 16 + (lane & 15), k0, lane);
#pragma unroll
        for (int ni = 0; ni < 4; ni++) {
            bf16x8 b = ldfrag96(wb, c0 + ni * 16 + (lane & 15), k0, lane);
#pragma unroll
            for (int mi = 0; mi < 4; mi++) acc[mi][ni] = MFMA(a[mi], b, acc[mi][ni]);
        }
    }
    int g = lane >> 4, cl = lane & 15;
#pragma unroll
    for (int ni = 0; ni < 4; ni++) {
        float bv = bias[c0 + ni * 16 + cl];
#pragma unroll
        for (int mi = 0; mi < 4; mi++)
#pragma unroll
            for (int r = 0; r < 4; r++) {
                float v = acc[mi][ni][r] + bv;
                h2[(size_t)(r0 + mi * 16 + g * 4 + r) * 256 + c0 + ni * 16 + cl] =
                    f2bu(v / (1.f + expf(-v)));
            }
    }
}

// ---------------------------------------------------------------------------
// Kernel G1 (MFMA): U = silu(X@w1^T) * (X@w2^T), bf16 everywhere, K=256
// ---------------------------------------------------------------------------
__global__ __launch_bounds__(256) void k_gemm_u(const u16* __restrict__ x,
                                                const u16* __restrict__ w1,
                                                const u16* __restrict__ w2,
                                                u16* __restrict__ U) {
    int lane = threadIdx.x & 63, wv = threadIdx.x >> 6;
    int r0 = blockIdx.x * 64;
    int c0 = blockIdx.y * 128 + wv * 32;
    f32x4 a1[4][2] = {}, a2[4][2] = {};
    for (int ks = 0; ks < 8; ks++) {
        int k0 = ks * 32;
        bf16x8 a[4];
#pragma unroll
        for (int mi = 0; mi < 4; mi++) a[mi] = ldfrag(x, r0 + mi * 16 + (lane & 15), k0, lane);
#pragma unroll
        for (int ni = 0; ni < 2; ni++) {
            bf16x8 b1 = ldfrag(w1, c0 + ni * 16 + (lane & 15), k0, lane);
            bf16x8 b2 = ldfrag(w2, c0 + ni * 16 + (lane & 15), k0, lane);
#pragma unroll
            for (int mi = 0; mi < 4; mi++) {
                a1[mi][ni] = MFMA(a[mi], b1, a1[mi][ni]);
                a2[mi][ni] = MFMA(a[mi], b2, a2[mi][ni]);
            }
        }
    }
    int g = lane >> 4, cl = lane & 15;
#pragma unroll
    for (int mi = 0; mi < 4; mi++)
#pragma unroll
        for (int ni = 0; ni < 2; ni++)
#pragma unroll
            for (int r = 0; r < 4; r++) {
                float v1 = a1[mi][ni][r], v2 = a2[mi][ni][r];
                float u = v1 / (1.f + expf(-v1)) * v2;
                U[(size_t)(r0 + mi * 16 + g * 4 + r) * 256 + c0 + ni * 16 + cl] = f2bu(u);
            }
}

// ---------------------------------------------------------------------------
// Kernel G2 (MFMA): hh = U@wp^T; V = hh + X; h3 = LN(V), bf16 out.
// ---------------------------------------------------------------------------
__global__ __launch_bounds__(256) void k_gemm_proj(const u16* __restrict__ U,
                                                   const u16* __restrict__ wp,
                                                   const u16* __restrict__ x,
                                                   const float* __restrict__ lnw,
                                                   const float* __restrict__ lnb,
                                                   u16* __restrict__ h3) {
    __shared__ float redS[64][4], redQ[64][4];
    int lane = threadIdx.x & 63, wv = threadIdx.x >> 6;
    int r0 = blockIdx.x * 64;
    int c0 = wv * 64;
    f32x4 acc[4][4] = {};
    for (int ks = 0; ks < 8; ks++) {
        int k0 = ks * 32;
        bf16x8 a[4];
#pragma unroll
        for (int mi = 0; mi < 4; mi++) a[mi] = ldfrag(U, r0 + mi * 16 + (lane & 15), k0, lane);
#pragma unroll
        for (int ni = 0; ni < 4; ni++) {
            bf16x8 b = ldfrag(wp, c0 + ni * 16 + (lane & 15), k0, lane);
#pragma unroll
            for (int mi = 0; mi < 4; mi++) acc[mi][ni] = MFMA(a[mi], b, acc[mi][ni]);
        }
    }
    int g = lane >> 4, cl = lane & 15;
#pragma unroll
    for (int mi = 0; mi < 4; mi++)
#pragma unroll
        for (int r = 0; r < 4; r++) {
            float s = 0.f, q = 0.f;
            int row = mi * 16 + g * 4 + r;
#pragma unroll
            for (int ni = 0; ni < 4; ni++) {
                int col = c0 + ni * 16 + cl;
                float v = acc[mi][ni][r] + b2f(x[(size_t)(r0 + row) * 256 + col]);
                acc[mi][ni][r] = v;
                s += v; q += v * v;
            }
            for (int m = 1; m < 16; m <<= 1) {
                s += __shfl_xor(s, m, 64);
                q += __shfl_xor(q, m, 64);
            }
            if (cl == 0) { redS[row][wv] = s; redQ[row][wv] = q; }
        }
    __syncthreads();

    float lw[4], lb[4];
#pragma unroll
    for (int ni = 0; ni < 4; ni++) {
        lw[ni] = lnw[c0 + ni * 16 + cl];
        lb[ni] = lnb[c0 + ni * 16 + cl];
    }
#pragma unroll
    for (int mi = 0; mi < 4; mi++)
#pragma unroll
        for (int r = 0; r < 4; r++) {
            int row = mi * 16 + g * 4 + r;
            float S = redS[row][0] + redS[row][1] + redS[row][2] + redS[row][3];
            float Q = redQ[row][0] + redQ[row][1] + redQ[row][2] + redQ[row][3];
            float m = S * (1.f / 256.f);
            float rs = rsqrtf(Q * (1.f / 256.f) - m * m + 1e-5f);
#pragma unroll
            for (int ni = 0; ni < 4; ni++) {
                float y = (acc[mi][ni][r] - m) * rs * lw[ni] + lb[ni];
                h3[(size_t)(r0 + row) * 256 + c0 + ni * 16 + cl] = f2bu(y);
            }
        }
}

// ---------------------------------------------------------------------------
// Kernel H (MFMA): out = h3 @ out_w^T + out_b. LDS-staged 128x128 tile,
// BK=32, double-buffered, padded LDS rows (stride 40 u16 = 80 B: reads are
// 2-way/free, writes at the 16B/lane floor). Staging for step kt+1 issued
// before compute of step kt (latency hidden under MFMA). Grid (512,8):
// x-fastest => 512 consecutive blocks share the B panel (L2-resident).
// ---------------------------------------------------------------------------
#define SA 40
__global__ __launch_bounds__(256) void k_out3(const u16* __restrict__ h3,
                                              const u16* __restrict__ ow,
                                              const float* __restrict__ bias,
                                              float* __restrict__ out) {
    __shared__ u16 As[2][128 * SA];
    __shared__ u16 Bs[2][128 * SA];
    int tid = threadIdx.x, lane = tid & 63, wv = tid >> 6;
    int r0 = blockIdx.x * 128;
    int c0g = blockIdx.y * 128;
    int wr = (wv >> 1) * 64, wc = (wv & 1) * 64;
    int rl = lane & 15, g = lane >> 4;

    // staging: 512 chunks of 16B per operand tile (128 rows x 4 chunks)
    int row0_ = tid >> 2, cc0_ = tid & 3;          // chunk tid
    int row1_ = (tid + 256) >> 2, cc1_ = tid & 3;  // chunk tid+256
    bf16x8 rA0, rA1, rB0, rB1;

#define LOADT(kt)                                                                     \
    {                                                                                 \
        int kbase = (kt) * 32;                                                        \
        rA0 = *(const bf16x8*)(h3 + (size_t)(r0 + row0_) * 256 + kbase + cc0_ * 8);   \
        rA1 = *(const bf16x8*)(h3 + (size_t)(r0 + row1_) * 256 + kbase + cc1_ * 8);   \
        rB0 = *(const bf16x8*)(ow + (size_t)(c0g + row0_) * 256 + kbase + cc0_ * 8);  \
        rB1 = *(const bf16x8*)(ow + (size_t)(c0g + row1_) * 256 + kbase + cc1_ * 8);  \
    }
#define WRITET(buf)                                                                   \
    {                                                                                 \
        *(bf16x8*)&As[buf][row0_ * SA + cc0_ * 8] = rA0;                              \
        *(bf16x8*)&As[buf][row1_ * SA + cc1_ * 8] = rA1;                              \
        *(bf16x8*)&Bs[buf][row0_ * SA + cc0_ * 8] = rB0;                              \
        *(bf16x8*)&Bs[buf][row1_ * SA + cc1_ * 8] = rB1;                              \
    }

    LOADT(0);
    WRITET(0);
    f32x4 acc[4][4] = {};
    for (int kt = 0; kt < 8; kt++) {
        int buf = kt & 1;
        if (kt < 7) LOADT(kt + 1);
        __syncthreads();
        bf16x8 a[4], b[4];
#pragma unroll
        for (int mi = 0; mi < 4; mi++) a[mi] = *(const bf16x8*)&As[buf][(wr + mi * 16 + rl) * SA + g * 8];
#pragma unroll
        for (int ni = 0; ni < 4; ni++) b[ni] = *(const bf16x8*)&Bs[buf][(wc + ni * 16 + rl) * SA + g * 8];
#pragma unroll
        for (int ni = 0; ni < 4; ni++)
#pragma unroll
            for (int mi = 0; mi < 4; mi++) acc[mi][ni] = MFMA(a[mi], b[ni], acc[mi][ni]);
        if (kt < 7) WRITET(buf ^ 1);
    }
#undef LOADT
#undef WRITET

    int cl = lane & 15;
#pragma unroll
    for (int ni = 0; ni < 4; ni++) {
        float bv = bias[c0g + wc + ni * 16 + cl];
#pragma unroll
        for (int mi = 0; mi < 4; mi++)
#pragma unroll
            for (int r = 0; r < 4; r++)
                out[(size_t)(r0 + wr + mi * 16 + g * 4 + r) * VV + c0g + wc + ni * 16 + cl] =
                    acc[mi][ni][r] + bv;
    }
}

// ---------------------------------------------------------------------------
extern "C" void kernel_launch(void* const* d_in, const int* in_sizes, int n_in,
                              void* d_out, int out_size, void* d_ws, size_t ws_size,
                              hipStream_t stream) {
    const int* chars        = (const int*)d_in[0];
    const float* byte_embed = (const float*)d_in[1];
    const float* table0     = (const float*)d_in[2];
    const float* table1     = (const float*)d_in[3];
    const float* table2     = (const float*)d_in[4];
    const float* table3     = (const float*)d_in[5];
    const float* cond_w     = (const float*)d_in[6];
    const float* conv_w     = (const float*)d_in[7];
    const float* conv_b     = (const float*)d_in[8];
    const float* gate_w     = (const float*)d_in[9];
    const float* gate_b     = (const float*)d_in[10];
    const float* inpr_w     = (const float*)d_in[11];
    const float* inpr_b     = (const float*)d_in[12];
    const float* outpr_w    = (const float*)d_in[13];
    const float* outpr_b    = (const float*)d_in[14];
    const float* scan_ln_w  = (const float*)d_in[15];
    const float* scan_ln_b  = (const float*)d_in[16];
    const float* inp_w      = (const float*)d_in[17];
    const float* inp_b      = (const float*)d_in[18];
    const float* r_w1       = (const float*)d_in[19];
    const float* r_w2       = (const float*)d_in[20];
    const float* r_proj     = (const float*)d_in[21];
    const float* r_ln_w     = (const float*)d_in[22];
    const float* r_ln_b     = (const float*)d_in[23];
    const float* out_w      = (const float*)d_in[24];
    const float* out_b      = (const float*)d_in[25];

    // ws layout with lifetimes (peak 68.2 MB):
    //   wbf  [0, 0.97M)       prep..end (bf16 weights incl. padded inp_w)
    //   hf   [1M, 24.1M)      feat..post
    //   raw  [24.1M, 26.2M)   hash..feat
    //   Ag   [24.1M, 32.5M)   gates..scan
    //   Dr   [32.5M, 40.9M)   gates..scan
    //   st   [40.9M, 49.3M)   scan..post
    //   h1p  [49.3M, 61.9M)   post..mlp1m (bf16, stride 96)
    //   h2b  [1M, 34.6M)      mlp1m..gemm_proj (over hf/Ag/Dr-head: dead)
    //   Ub   [34.6M, 68.2M)   gemm_u..gemm_proj (over Dr-tail/st/h1p: dead)
    //   h3b  aliases Ub       gemm_proj..out3 (row-for-row, safe)
    char* ws = (char*)d_ws;
    u16*   wbf = (u16*)(ws + 0);
    u16*   w1b = wbf;
    u16*   w2b = wbf + 65536;
    u16*   wpb = wbf + 131072;
    u16*   owb = wbf + 196608;
    u16*   iwb = wbf + 458752;
    float* hf  = (float*)(ws + 1048576);
    float* raw = (float*)(ws + 24117248);
    float* Ag  = (float*)(ws + 24117248);
    float* Dr  = (float*)(ws + 32505856);
    float* st  = (float*)(ws + 40894464);
    u16*   h1p = (u16*)(ws + 49283072);
    u16*   h2b = (u16*)(ws + 1048576);
    u16*   Ub  = (u16*)(ws + 34603008);
    u16*   h3b = (u16*)(ws + 34603008);
    float* out = (float*)d_out;

    k_prep <<<1888, 256, 0, stream>>>(r_w1, r_w2, r_proj, out_w, inp_w, wbf);
    k_hash <<<256, 256, 0, stream>>>(chars, table0, table1, table2, table3, cond_w, raw);
    k_feat <<<256, 256, 0, stream>>>(chars, byte_embed, raw, conv_w, conv_b, hf);
    k_gates<<<1024, 256, 0, stream>>>(hf, gate_w, gate_b, inpr_w, inpr_b, Ag, Dr);
    k_scan_par<<<1024, 64, 0, stream>>>(Ag, Dr, st);
    k_post <<<256, 256, 0, stream>>>(st, hf, outpr_w, outpr_b, scan_ln_w, scan_ln_b, h1p);
    k_mlp1m<<<1024, 256, 0, stream>>>(h1p, iwb, inp_b, h2b);
    k_gemm_u   <<<dim3(1024, 2), 256, 0, stream>>>(h2b, w1b, w2b, Ub);
    k_gemm_proj<<<1024, 256, 0, stream>>>(Ub, wpb, h2b, r_ln_w, r_ln_b, h3b);
    k_out3     <<<dim3(512, 8), 256, 0, stream>>>(h3b, owb, out_b, out);
}

// Round 9
// 381.591 us; speedup vs baseline: 9.3876x; 1.0413x over previous
//
#include <hip/hip_runtime.h>

#define BB 32
#define TT 2048
#define SS 32
#define DD 80
#define HH 256
#define VV 1024
#define EBD 64

typedef unsigned short u16;
typedef __attribute__((ext_vector_type(8))) __bf16 bf16x8;
typedef __attribute__((ext_vector_type(4))) float f32x4;

#define MFMA(a, b, c) __builtin_amdgcn_mfma_f32_16x16x32_bf16(a, b, c, 0, 0, 0)

__device__ inline u16 f2bu(float f) {
    unsigned u = __float_as_uint(f);
    return (u16)((u + 0x7FFFu + ((u >> 16) & 1u)) >> 16);
}
__device__ inline __bf16 f2b(float f) {
    u16 r = f2bu(f);
    return __builtin_bit_cast(__bf16, r);
}
__device__ inline float b2f(u16 h) { return __uint_as_float(((unsigned)h) << 16); }

// A/B fragment (16 rows x 32 k) from bf16 row-major [.][256]
__device__ inline bf16x8 ldfrag(const u16* base, int row, int k0, int lane) {
    return *(const bf16x8*)(base + (size_t)row * 256 + k0 + ((lane >> 4) << 3));
}
// same from row-major [.][96]
__device__ inline bf16x8 ldfrag96(const u16* base, int row, int k0, int lane) {
    return *(const bf16x8*)(base + (size_t)row * 96 + k0 + ((lane >> 4) << 3));
}

// ---------------------------------------------------------------------------
// Kernel P: convert GEMM weights f32 -> bf16 once per launch. (round-6 exact)
// wbf: r_w1[0,64K) r_w2[64K,128K) r_proj[128K,192K) out_w[192K,448K)
//      inp_w padded [256][96] at [448K, 472K)
// ---------------------------------------------------------------------------
__global__ __launch_bounds__(256) void k_prep(const float* __restrict__ w1,
                                              const float* __restrict__ w2,
                                              const float* __restrict__ wp,
                                              const float* __restrict__ ow,
                                              const float* __restrict__ iw,
                                              u16* __restrict__ wbf) {
    int i = blockIdx.x * 256 + threadIdx.x;
    if (i >= 483328) return;
    float v;
    if (i < 65536) v = w1[i];
    else if (i < 131072) v = w2[i - 65536];
    else if (i < 196608) v = wp[i - 131072];
    else if (i < 458752) v = ow[i - 196608];
    else {
        int j = i - 458752;
        int row = j / 96, col = j % 96;
        v = (col < 80) ? iw[row * 80 + col] : 0.f;
    }
    wbf[i] = f2bu(v);
}

// ---------------------------------------------------------------------------
// Kernel A: polynomial rolling hashes + table gathers (round-6 exact)
// ---------------------------------------------------------------------------
__global__ __launch_bounds__(256) void k_hash(const int* __restrict__ tok,
                                              const float* __restrict__ t0,
                                              const float* __restrict__ t1,
                                              const float* __restrict__ t2,
                                              const float* __restrict__ t3,
                                              const float* __restrict__ cond_w,
                                              float* __restrict__ raw) {
    int idx = blockIdx.x * 256 + threadIdx.x;
    if (idx >= BB * TT) return;
    int b = idx / TT, t = idx % TT;
    const int* tr = tok + b * TT;

    unsigned long long tv[8];
#pragma unroll
    for (int i = 0; i < 8; i++) {
        int ts = t - 1 - i;
        tv[i] = (ts >= 0) ? (unsigned long long)(unsigned)tr[ts] : 0ull;
    }
    const unsigned long long P[8] = {2654435761ull, 2246822519ull, 3266489917ull,
                                     2028178513ull, 1220703125ull, 1610612741ull,
                                     805306457ull, 402653189ull};
    unsigned long long x = 0ull;
    x ^= tv[0] * P[0]; unsigned long long k0 = x % 2000000ull;
    x ^= tv[1] * P[1]; unsigned long long k1 = x % 2000000ull;
    x ^= tv[2] * P[2]; x ^= tv[3] * P[3]; unsigned long long k2 = x % 2000000ull;
    x ^= tv[4] * P[4]; x ^= tv[5] * P[5];
    x ^= tv[6] * P[6]; x ^= tv[7] * P[7]; unsigned long long k3 = x % 2000000ull;

    float f0 = t0[k0 * 2], f1 = t0[k0 * 2 + 1];
    float f2 = t1[k1 * 2], f3 = t1[k1 * 2 + 1];

    unsigned long long ck = 0ull;
#pragma unroll
    for (int j = 0; j < 8; j++) {
        float lg = f0 * cond_w[j * 4 + 0] + f1 * cond_w[j * 4 + 1] +
                   f2 * cond_w[j * 4 + 2] + f3 * cond_w[j * 4 + 3];
        if (lg > 0.f) ck ^= P[j];
    }
    unsigned long long lk2 = (k2 ^ ck) % 2000000ull;
    unsigned long long lk3 = (k3 ^ ck) % 2000000ull;

    float* o = raw + (size_t)idx * 8;
    o[0] = f0; o[1] = f1; o[2] = f2; o[3] = f3;
    o[4] = t2[lk2 * 2]; o[5] = t2[lk2 * 2 + 1];
    o[6] = t3[lk3 * 2]; o[7] = t3[lk3 * 2 + 1];
}

// ---------------------------------------------------------------------------
// Kernel B: conv + silu + assemble h[b,t,80] f32 (round-6 semantics;
// embed copy vectorized f32x4 — bit-identical values)
// ---------------------------------------------------------------------------
__global__ __launch_bounds__(256) void k_feat(const int* __restrict__ tok,
                                              const float* __restrict__ be,
                                              const float* __restrict__ raw,
                                              const float* __restrict__ conv_w,
                                              const float* __restrict__ conv_b,
                                              float* __restrict__ hf) {
    int idx = blockIdx.x * 256 + threadIdx.x;
    if (idx >= BB * TT) return;
    int b = idx / TT, t = idx % TT;
    const int* tr = tok + b * TT;
    float* o = hf + (size_t)idx * DD;

    int tk = tr[t];
    const float* ber = be + (size_t)tk * EBD;
#pragma unroll
    for (int q = 0; q < 16; q++) *(f32x4*)(o + q * 4) = *(const f32x4*)(ber + q * 4);

#pragma unroll
    for (int c = 0; c < 8; c++) {
        float acc = conv_b[c];
#pragma unroll
        for (int k = 0; k < 8; k++) {
            int ts = t - 7 + k;
            if (ts >= 0) acc += conv_w[c * 8 + k] * raw[((size_t)(b * TT + ts)) * 8 + c];
        }
        o[64 + c] = acc / (1.f + expf(-acc));
    }

#pragma unroll
    for (int k = 1; k <= 8; k++) {
        float m = (t >= k && tk == tr[t - k]) ? 1.f : 0.f;
        o[71 + k] = m;
    }
}

// ---------------------------------------------------------------------------
// Kernel C: scan gates (round-6 arithmetic, weights LDS-staged; pad 81
// makes the s-indexed reads conflict-free. Bit-identical results.)
// ---------------------------------------------------------------------------
__global__ __launch_bounds__(256) void k_gates(const float* __restrict__ hf,
                                               const float* __restrict__ gw,
                                               const float* __restrict__ gb,
                                               const float* __restrict__ iw,
                                               const float* __restrict__ ib,
                                               float* __restrict__ Ag,
                                               float* __restrict__ Dr) {
    __shared__ float xs[64][DD];
    __shared__ float gws[32 * 81];
    __shared__ float iws[32 * 81];
    int blk = blockIdx.x;
    int b = blk >> 5;
    int t0 = (blk & 31) << 6;
    const float* src = hf + ((size_t)(b * TT + t0)) * DD;
    for (int i = threadIdx.x; i < 64 * DD; i += 256) xs[i / DD][i % DD] = src[i];
    for (int i = threadIdx.x; i < 32 * 80; i += 256) {
        int s = i / 80, d = i % 80;
        gws[s * 81 + d] = gw[i];
        iws[s * 81 + d] = iw[i];
    }
    __syncthreads();

    for (int p = threadIdx.x; p < 64 * SS; p += 256) {
        int s = p & 31, tt = p >> 5;
        float ga = gb[s], ia = ib[s];
        for (int d = 0; d < DD; d++) {
            float xv = xs[tt][d];
            ga += xv * gws[s * 81 + d];
            ia += xv * iws[s * 81 + d];
        }
        float g = 1.f / (1.f + expf(-ga));
        float drv = (1.f - g) * ia;
        size_t oo = ((size_t)(b * SS + s)) * TT + t0 + tt;
        Ag[oo] = g;
        Dr[oo] = drv;
    }
}

// ---------------------------------------------------------------------------
// Kernel D: parallel chunked scan (round-6 exact)
// ---------------------------------------------------------------------------
__global__ __launch_bounds__(64) void k_scan_par(const float* __restrict__ Ag,
                                                 const float* __restrict__ Dr,
                                                 float* __restrict__ st) {
    int bs = blockIdx.x;
    int b = bs >> 5, s = bs & 31;
    int c = threadIdx.x;
    const float* ar = Ag + (size_t)bs * TT + c * 32;
    const float* dr = Dr + (size_t)bs * TT + c * 32;

    float ca[32], cw[32];
    float lacc = 0.f, wacc = 0.f;
#pragma unroll
    for (int k = 0; k < 32; k += 4) {
        f32x4 av = *(const f32x4*)(ar + k);
        f32x4 dv = *(const f32x4*)(dr + k);
#pragma unroll
        for (int j = 0; j < 4; j++) {
            lacc += logf(fmaxf(av[j], 1e-6f));
            float cav = expf(lacc);
            ca[k + j] = cav;
            wacc += dv[j] / fmaxf(cav, 1e-8f);
            cw[k + j] = wacc;
        }
    }

    float A = ca[31];
    float Bc = ca[31] * wacc;
    for (int off = 1; off < 64; off <<= 1) {
        float Ap = __shfl_up(A, off, 64);
        float Bp = __shfl_up(Bc, off, 64);
        if (c >= off) {
            Bc = A * Bp + Bc;
            A = A * Ap;
        }
    }
    float h0 = __shfl_up(Bc, 1, 64);
    if (c == 0) h0 = 0.f;

    float* op = st + ((size_t)(b * TT + c * 32)) * SS + s;
#pragma unroll
    for (int k = 0; k < 32; k++)
        op[(size_t)k * SS] = ca[k] * (h0 + cw[k]);
}

// ---------------------------------------------------------------------------
// Kernel E: y = st @ outpr_w^T + ob; h1 = LN(hf + y) -> h1p bf16[96].
// Round-6 two-pass f32 arithmetic bit-identical; outpr_w LDS-staged
// (wave-broadcast reads, conflict-free), st loads f32x4.
// ---------------------------------------------------------------------------
__global__ __launch_bounds__(256) void k_post(const float* __restrict__ st,
                                              const float* __restrict__ hf,
                                              const float* __restrict__ ow,
                                              const float* __restrict__ ob,
                                              const float* __restrict__ lnw,
                                              const float* __restrict__ lnb,
                                              u16* __restrict__ h1p) {
    __shared__ float ows[DD * SS];
    for (int i = threadIdx.x; i < DD * SS; i += 256) ows[i] = ow[i];
    __syncthreads();

    int idx = blockIdx.x * 256 + threadIdx.x;
    if (idx >= BB * TT) return;
    const float* sp = st + (size_t)idx * SS;
    float sv[SS];
#pragma unroll
    for (int i = 0; i < SS; i += 4) {
        f32x4 v4 = *(const f32x4*)(sp + i);
        sv[i] = v4[0]; sv[i + 1] = v4[1]; sv[i + 2] = v4[2]; sv[i + 3] = v4[3];
    }
    const float* x = hf + (size_t)idx * DD;

    float s1 = 0.f, s2 = 0.f;
    for (int d = 0; d < DD; d++) {
        float acc = ob[d];
#pragma unroll
        for (int i = 0; i < SS; i++) acc += sv[i] * ows[d * SS + i];
        float v = acc + x[d];
        s1 += v; s2 += v * v;
    }
    float m = s1 * (1.f / DD);
    float var = s2 * (1.f / DD) - m * m;
    float rs = rsqrtf(var + 1e-5f);
    u16* o = h1p + (size_t)idx * 96;
    for (int d = 0; d < DD; d++) {
        float acc = ob[d];
#pragma unroll
        for (int i = 0; i < SS; i++) acc += sv[i] * ows[d * SS + i];
        float v = acc + x[d];
        o[d] = f2bu((v - m) * rs * lnw[d] + lnb[d]);
    }
    *(f32x4*)(o + 80) = f32x4{0.f, 0.f, 0.f, 0.f};
    *(f32x4*)(o + 88) = f32x4{0.f, 0.f, 0.f, 0.f};
}

// ---------------------------------------------------------------------------
// Kernel F (MFMA): h2 = silu(h1p @ inp_w_b^T + inp_b), K=96 (round-6 exact)
// ---------------------------------------------------------------------------
__global__ __launch_bounds__(256) void k_mlp1m(const u16* __restrict__ h1p,
                                               const u16* __restrict__ wb,
                                               const float* __restrict__ bias,
                                               u16* __restrict__ h2) {
    int lane = threadIdx.x & 63, wv = threadIdx.x >> 6;
    int r0 = blockIdx.x * 64;
    int c0 = wv * 64;
    f32x4 acc[4][4] = {};
#pragma unroll
    for (int ks = 0; ks < 3; ks++) {
        int k0 = ks * 32;
        bf16x8 a[4];
#pragma unroll
        for (int mi = 0; mi < 4; mi++) a[mi] = ldfrag96(h1p, r0 + mi * 16 + (lane & 15), k0, lane);
#pragma unroll
        for (int ni = 0; ni < 4; ni++) {
            bf16x8 b = ldfrag96(wb, c0 + ni * 16 + (lane & 15), k0, lane);
#pragma unroll
            for (int mi = 0; mi < 4; mi++) acc[mi][ni] = MFMA(a[mi], b, acc[mi][ni]);
        }
    }
    int g = lane >> 4, cl = lane & 15;
#pragma unroll
    for (int ni = 0; ni < 4; ni++) {
        float bv = bias[c0 + ni * 16 + cl];
#pragma unroll
        for (int mi = 0; mi < 4; mi++)
#pragma unroll
            for (int r = 0; r < 4; r++) {
                float v = acc[mi][ni][r] + bv;
                h2[(size_t)(r0 + mi * 16 + g * 4 + r) * 256 + c0 + ni * 16 + cl] =
                    f2bu(v / (1.f + expf(-v)));
            }
    }
}

// ---------------------------------------------------------------------------
// Kernel G1 (MFMA): U = silu(X@w1^T) * (X@w2^T), K=256 (round-6 exact)
// ---------------------------------------------------------------------------
__global__ __launch_bounds__(256) void k_gemm_u(const u16* __restrict__ x,
                                                const u16* __restrict__ w1,
                                                const u16* __restrict__ w2,
                                                u16* __restrict__ U) {
    int lane = threadIdx.x & 63, wv = threadIdx.x >> 6;
    int r0 = blockIdx.x * 64;
    int c0 = blockIdx.y * 128 + wv * 32;
    f32x4 a1[4][2] = {}, a2[4][2] = {};
    for (int ks = 0; ks < 8; ks++) {
        int k0 = ks * 32;
        bf16x8 a[4];
#pragma unroll
        for (int mi = 0; mi < 4; mi++) a[mi] = ldfrag(x, r0 + mi * 16 + (lane & 15), k0, lane);
#pragma unroll
        for (int ni = 0; ni < 2; ni++) {
            bf16x8 b1 = ldfrag(w1, c0 + ni * 16 + (lane & 15), k0, lane);
            bf16x8 b2 = ldfrag(w2, c0 + ni * 16 + (lane & 15), k0, lane);
#pragma unroll
            for (int mi = 0; mi < 4; mi++) {
                a1[mi][ni] = MFMA(a[mi], b1, a1[mi][ni]);
                a2[mi][ni] = MFMA(a[mi], b2, a2[mi][ni]);
            }
        }
    }
    int g = lane >> 4, cl = lane & 15;
#pragma unroll
    for (int mi = 0; mi < 4; mi++)
#pragma unroll
        for (int ni = 0; ni < 2; ni++)
#pragma unroll
            for (int r = 0; r < 4; r++) {
                float v1 = a1[mi][ni][r], v2 = a2[mi][ni][r];
                float u = v1 / (1.f + expf(-v1)) * v2;
                U[(size_t)(r0 + mi * 16 + g * 4 + r) * 256 + c0 + ni * 16 + cl] = f2bu(u);
            }
}

// ---------------------------------------------------------------------------
// Kernel G2 (MFMA): hh = U@wp^T; V = hh + X; h3 = LN(V) (round-6 exact)
// ---------------------------------------------------------------------------
__global__ __launch_bounds__(256) void k_gemm_proj(const u16* __restrict__ U,
                                                   const u16* __restrict__ wp,
                                                   const u16* __restrict__ x,
                                                   const float* __restrict__ lnw,
                                                   const float* __restrict__ lnb,
                                                   u16* __restrict__ h3) {
    __shared__ float redS[64][4], redQ[64][4];
    int lane = threadIdx.x & 63, wv = threadIdx.x >> 6;
    int r0 = blockIdx.x * 64;
    int c0 = wv * 64;
    f32x4 acc[4][4] = {};
    for (int ks = 0; ks < 8; ks++) {
        int k0 = ks * 32;
        bf16x8 a[4];
#pragma unroll
        for (int mi = 0; mi < 4; mi++) a[mi] = ldfrag(U, r0 + mi * 16 + (lane & 15), k0, lane);
#pragma unroll
        for (int ni = 0; ni < 4; ni++) {
            bf16x8 b = ldfrag(wp, c0 + ni * 16 + (lane & 15), k0, lane);
#pragma unroll
            for (int mi = 0; mi < 4; mi++) acc[mi][ni] = MFMA(a[mi], b, acc[mi][ni]);
        }
    }
    int g = lane >> 4, cl = lane & 15;
#pragma unroll
    for (int mi = 0; mi < 4; mi++)
#pragma unroll
        for (int r = 0; r < 4; r++) {
            float s = 0.f, q = 0.f;
            int row = mi * 16 + g * 4 + r;
#pragma unroll
            for (int ni = 0; ni < 4; ni++) {
                int col = c0 + ni * 16 + cl;
                float v = acc[mi][ni][r] + b2f(x[(size_t)(r0 + row) * 256 + col]);
                acc[mi][ni][r] = v;
                s += v; q += v * v;
            }
            for (int m = 1; m < 16; m <<= 1) {
                s += __shfl_xor(s, m, 64);
                q += __shfl_xor(q, m, 64);
            }
            if (cl == 0) { redS[row][wv] = s; redQ[row][wv] = q; }
        }
    __syncthreads();

    float lw[4], lb[4];
#pragma unroll
    for (int ni = 0; ni < 4; ni++) {
        lw[ni] = lnw[c0 + ni * 16 + cl];
        lb[ni] = lnb[c0 + ni * 16 + cl];
    }
#pragma unroll
    for (int mi = 0; mi < 4; mi++)
#pragma unroll
        for (int r = 0; r < 4; r++) {
            int row = mi * 16 + g * 4 + r;
            float S = redS[row][0] + redS[row][1] + redS[row][2] + redS[row][3];
            float Q = redQ[row][0] + redQ[row][1] + redQ[row][2] + redQ[row][3];
            float m = S * (1.f / 256.f);
            float rs = rsqrtf(Q * (1.f / 256.f) - m * m + 1e-5f);
#pragma unroll
            for (int ni = 0; ni < 4; ni++) {
                float y = (acc[mi][ni][r] - m) * rs * lw[ni] + lb[ni];
                h3[(size_t)(r0 + row) * 256 + c0 + ni * 16 + cl] = f2bu(y);
            }
        }
}

// ---------------------------------------------------------------------------
// Kernel H (MFMA): out = h3 @ out_w^T + out_b, LDS-staged 128x128 (round-6)
// ---------------------------------------------------------------------------
#define SA 40
__global__ __launch_bounds__(256) void k_out3(const u16* __restrict__ h3,
                                              const u16* __restrict__ ow,
                                              const float* __restrict__ bias,
                                              float* __restrict__ out) {
    __shared__ u16 As[2][128 * SA];
    __shared__ u16 Bs[2][128 * SA];
    int tid = threadIdx.x, lane = tid & 63, wv = tid >> 6;
    int r0 = blockIdx.x * 128;
    int c0g = blockIdx.y * 128;
    int wr = (wv >> 1) * 64, wc = (wv & 1) * 64;
    int rl = lane & 15, g = lane >> 4;

    int row0_ = tid >> 2, cc0_ = tid & 3;
    int row1_ = (tid + 256) >> 2, cc1_ = tid & 3;
    bf16x8 rA0, rA1, rB0, rB1;

#define LOADT(kt)                                                                     \
    {                                                                                 \
        int kbase = (kt) * 32;                                                        \
        rA0 = *(const bf16x8*)(h3 + (size_t)(r0 + row0_) * 256 + kbase + cc0_ * 8);   \
        rA1 = *(const bf16x8*)(h3 + (size_t)(r0 + row1_) * 256 + kbase + cc1_ * 8);   \
        rB0 = *(const bf16x8*)(ow + (size_t)(c0g + row0_) * 256 + kbase + cc0_ * 8);  \
        rB1 = *(const bf16x8*)(ow + (size_t)(c0g + row1_) * 256 + kbase + cc1_ * 8);  \
    }
#define WRITET(buf)                                                                   \
    {                                                                                 \
        *(bf16x8*)&As[buf][row0_ * SA + cc0_ * 8] = rA0;                              \
        *(bf16x8*)&As[buf][row1_ * SA + cc1_ * 8] = rA1;                              \
        *(bf16x8*)&Bs[buf][row0_ * SA + cc0_ * 8] = rB0;                              \
        *(bf16x8*)&Bs[buf][row1_ * SA + cc1_ * 8] = rB1;                              \
    }

    LOADT(0);
    WRITET(0);
    f32x4 acc[4][4] = {};
    for (int kt = 0; kt < 8; kt++) {
        int buf = kt & 1;
        if (kt < 7) LOADT(kt + 1);
        __syncthreads();
        bf16x8 a[4], b[4];
#pragma unroll
        for (int mi = 0; mi < 4; mi++) a[mi] = *(const bf16x8*)&As[buf][(wr + mi * 16 + rl) * SA + g * 8];
#pragma unroll
        for (int ni = 0; ni < 4; ni++) b[ni] = *(const bf16x8*)&Bs[buf][(wc + ni * 16 + rl) * SA + g * 8];
#pragma unroll
        for (int ni = 0; ni < 4; ni++)
#pragma unroll
            for (int mi = 0; mi < 4; mi++) acc[mi][ni] = MFMA(a[mi], b[ni], acc[mi][ni]);
        if (kt < 7) WRITET(buf ^ 1);
    }
#undef LOADT
#undef WRITET

    int cl = lane & 15;
#pragma unroll
    for (int ni = 0; ni < 4; ni++) {
        float bv = bias[c0g + wc + ni * 16 + cl];
#pragma unroll
        for (int mi = 0; mi < 4; mi++)
#pragma unroll
            for (int r = 0; r < 4; r++)
                out[(size_t)(r0 + wr + mi * 16 + g * 4 + r) * VV + c0g + wc + ni * 16 + cl] =
                    acc[mi][ni][r] + bv;
    }
}

// ---------------------------------------------------------------------------
extern "C" void kernel_launch(void* const* d_in, const int* in_sizes, int n_in,
                              void* d_out, int out_size, void* d_ws, size_t ws_size,
                              hipStream_t stream) {
    const int* chars        = (const int*)d_in[0];
    const float* byte_embed = (const float*)d_in[1];
    const float* table0     = (const float*)d_in[2];
    const float* table1     = (const float*)d_in[3];
    const float* table2     = (const float*)d_in[4];
    const float* table3     = (const float*)d_in[5];
    const float* cond_w     = (const float*)d_in[6];
    const float* conv_w     = (const float*)d_in[7];
    const float* conv_b     = (const float*)d_in[8];
    const float* gate_w     = (const float*)d_in[9];
    const float* gate_b     = (const float*)d_in[10];
    const float* inpr_w     = (const float*)d_in[11];
    const float* inpr_b     = (const float*)d_in[12];
    const float* outpr_w    = (const float*)d_in[13];
    const float* outpr_b    = (const float*)d_in[14];
    const float* scan_ln_w  = (const float*)d_in[15];
    const float* scan_ln_b  = (const float*)d_in[16];
    const float* inp_w      = (const float*)d_in[17];
    const float* inp_b      = (const float*)d_in[18];
    const float* r_w1       = (const float*)d_in[19];
    const float* r_w2       = (const float*)d_in[20];
    const float* r_proj     = (const float*)d_in[21];
    const float* r_ln_w     = (const float*)d_in[22];
    const float* r_ln_b     = (const float*)d_in[23];
    const float* out_w      = (const float*)d_in[24];
    const float* out_b      = (const float*)d_in[25];

    // ws layout (round-6 exact, peak 68.2 MB):
    //   wbf  [0, 0.97M)       prep..end
    //   hf   [1M, 24.1M)      feat..post (f32, stride 80)
    //   raw  [24.1M, 26.2M)   hash..feat
    //   Ag   [24.1M, 32.5M)   gates..scan (over raw after feat)
    //   Dr   [32.5M, 40.9M)   gates..scan
    //   st   [40.9M, 49.3M)   scan..post
    //   h1p  [49.3M, 61.9M)   post..mlp1m (bf16, stride 96)
    //   h2b  [1M, 34.6M)      mlp1m..gemm_proj (over hf/Ag/Dr-head: dead)
    //   Ub   [34.6M, 68.2M)   gemm_u..gemm_proj (over Dr-tail/st/h1p: dead)
    //   h3b  aliases Ub       gemm_proj..out3 (row-for-row, safe)
    char* ws = (char*)d_ws;
    u16*   wbf = (u16*)(ws + 0);
    u16*   w1b = wbf;
    u16*   w2b = wbf + 65536;
    u16*   wpb = wbf + 131072;
    u16*   owb = wbf + 196608;
    u16*   iwb = wbf + 458752;
    float* hf  = (float*)(ws + 1048576);
    float* raw = (float*)(ws + 24117248);
    float* Ag  = (float*)(ws + 24117248);
    float* Dr  = (float*)(ws + 32505856);
    float* st  = (float*)(ws + 40894464);
    u16*   h1p = (u16*)(ws + 49283072);
    u16*   h2b = (u16*)(ws + 1048576);
    u16*   Ub  = (u16*)(ws + 34603008);
    u16*   h3b = (u16*)(ws + 34603008);
    float* out = (float*)d_out;

    k_prep <<<1888, 256, 0, stream>>>(r_w1, r_w2, r_proj, out_w, inp_w, wbf);
    k_hash <<<256, 256, 0, stream>>>(chars, table0, table1, table2, table3, cond_w, raw);
    k_feat <<<256, 256, 0, stream>>>(chars, byte_embed, raw, conv_w, conv_b, hf);
    k_gates<<<1024, 256, 0, stream>>>(hf, gate_w, gate_b, inpr_w, inpr_b, Ag, Dr);
    k_scan_par<<<1024, 64, 0, stream>>>(Ag, Dr, st);
    k_post <<<256, 256, 0, stream>>>(st, hf, outpr_w, outpr_b, scan_ln_w, scan_ln_b, h1p);
    k_mlp1m<<<1024, 256, 0, stream>>>(h1p, iwb, inp_b, h2b);
    k_gemm_u   <<<dim3(1024, 2), 256, 0, stream>>>(h2b, w1b, w2b, Ub);
    k_gemm_proj<<<1024, 256, 0, stream>>>(Ub, wpb, h2b, r_ln_w, r_ln_b, h3b);
    k_out3     <<<dim3(512, 8), 256, 0, stream>>>(h3b, owb, out_b, out);
}

// Round 10
// 339.731 us; speedup vs baseline: 10.5443x; 1.1232x over previous
//
#include <hip/hip_runtime.h>

#define BB 32
#define TT 2048
#define SS 32
#define DD 80
#define HH 256
#define VV 1024
#define EBD 64

typedef unsigned short u16;
typedef __attribute__((ext_vector_type(8))) __bf16 bf16x8;
typedef __attribute__((ext_vector_type(4))) float f32x4;

#define MFMA(a, b, c) __builtin_amdgcn_mfma_f32_16x16x32_bf16(a, b, c, 0, 0, 0)

__device__ inline u16 f2bu(float f) {
    unsigned u = __float_as_uint(f);
    return (u16)((u + 0x7FFFu + ((u >> 16) & 1u)) >> 16);
}
__device__ inline __bf16 f2b(float f) {
    u16 r = f2bu(f);
    return __builtin_bit_cast(__bf16, r);
}
__device__ inline float b2f(u16 h) { return __uint_as_float(((unsigned)h) << 16); }

// A/B fragment (16 rows x 32 k) from bf16 row-major [.][256]
__device__ inline bf16x8 ldfrag(const u16* base, int row, int k0, int lane) {
    return *(const bf16x8*)(base + (size_t)row * 256 + k0 + ((lane >> 4) << 3));
}
// same from row-major [.][96]
__device__ inline bf16x8 ldfrag96(const u16* base, int row, int k0, int lane) {
    return *(const bf16x8*)(base + (size_t)row * 96 + k0 + ((lane >> 4) << 3));
}

// ---------------------------------------------------------------------------
// Kernel P: convert GEMM weights f32 -> bf16 once per launch. (round-9 exact)
// ---------------------------------------------------------------------------
__global__ __launch_bounds__(256) void k_prep(const float* __restrict__ w1,
                                              const float* __restrict__ w2,
                                              const float* __restrict__ wp,
                                              const float* __restrict__ ow,
                                              const float* __restrict__ iw,
                                              u16* __restrict__ wbf) {
    int i = blockIdx.x * 256 + threadIdx.x;
    if (i >= 483328) return;
    float v;
    if (i < 65536) v = w1[i];
    else if (i < 131072) v = w2[i - 65536];
    else if (i < 196608) v = wp[i - 131072];
    else if (i < 458752) v = ow[i - 196608];
    else {
        int j = i - 458752;
        int row = j / 96, col = j % 96;
        v = (col < 80) ? iw[row * 80 + col] : 0.f;
    }
    wbf[i] = f2bu(v);
}

// ---------------------------------------------------------------------------
// Kernel A: polynomial rolling hashes + table gathers (round-9 exact)
// ---------------------------------------------------------------------------
__global__ __launch_bounds__(256) void k_hash(const int* __restrict__ tok,
                                              const float* __restrict__ t0,
                                              const float* __restrict__ t1,
                                              const float* __restrict__ t2,
                                              const float* __restrict__ t3,
                                              const float* __restrict__ cond_w,
                                              float* __restrict__ raw) {
    int idx = blockIdx.x * 256 + threadIdx.x;
    if (idx >= BB * TT) return;
    int b = idx / TT, t = idx % TT;
    const int* tr = tok + b * TT;

    unsigned long long tv[8];
#pragma unroll
    for (int i = 0; i < 8; i++) {
        int ts = t - 1 - i;
        tv[i] = (ts >= 0) ? (unsigned long long)(unsigned)tr[ts] : 0ull;
    }
    const unsigned long long P[8] = {2654435761ull, 2246822519ull, 3266489917ull,
                                     2028178513ull, 1220703125ull, 1610612741ull,
                                     805306457ull, 402653189ull};
    unsigned long long x = 0ull;
    x ^= tv[0] * P[0]; unsigned long long k0 = x % 2000000ull;
    x ^= tv[1] * P[1]; unsigned long long k1 = x % 2000000ull;
    x ^= tv[2] * P[2]; x ^= tv[3] * P[3]; unsigned long long k2 = x % 2000000ull;
    x ^= tv[4] * P[4]; x ^= tv[5] * P[5];
    x ^= tv[6] * P[6]; x ^= tv[7] * P[7]; unsigned long long k3 = x % 2000000ull;

    float f0 = t0[k0 * 2], f1 = t0[k0 * 2 + 1];
    float f2 = t1[k1 * 2], f3 = t1[k1 * 2 + 1];

    unsigned long long ck = 0ull;
#pragma unroll
    for (int j = 0; j < 8; j++) {
        float lg = f0 * cond_w[j * 4 + 0] + f1 * cond_w[j * 4 + 1] +
                   f2 * cond_w[j * 4 + 2] + f3 * cond_w[j * 4 + 3];
        if (lg > 0.f) ck ^= P[j];
    }
    unsigned long long lk2 = (k2 ^ ck) % 2000000ull;
    unsigned long long lk3 = (k3 ^ ck) % 2000000ull;

    float* o = raw + (size_t)idx * 8;
    o[0] = f0; o[1] = f1; o[2] = f2; o[3] = f3;
    o[4] = t2[lk2 * 2]; o[5] = t2[lk2 * 2 + 1];
    o[6] = t3[lk3 * 2]; o[7] = t3[lk3 * 2 + 1];
}

// ---------------------------------------------------------------------------
// Kernel B: conv + silu + assemble h[b,t,80] f32 (round-9 exact)
// ---------------------------------------------------------------------------
__global__ __launch_bounds__(256) void k_feat(const int* __restrict__ tok,
                                              const float* __restrict__ be,
                                              const float* __restrict__ raw,
                                              const float* __restrict__ conv_w,
                                              const float* __restrict__ conv_b,
                                              float* __restrict__ hf) {
    int idx = blockIdx.x * 256 + threadIdx.x;
    if (idx >= BB * TT) return;
    int b = idx / TT, t = idx % TT;
    const int* tr = tok + b * TT;
    float* o = hf + (size_t)idx * DD;

    int tk = tr[t];
    const float* ber = be + (size_t)tk * EBD;
#pragma unroll
    for (int q = 0; q < 16; q++) *(f32x4*)(o + q * 4) = *(const f32x4*)(ber + q * 4);

#pragma unroll
    for (int c = 0; c < 8; c++) {
        float acc = conv_b[c];
#pragma unroll
        for (int k = 0; k < 8; k++) {
            int ts = t - 7 + k;
            if (ts >= 0) acc += conv_w[c * 8 + k] * raw[((size_t)(b * TT + ts)) * 8 + c];
        }
        o[64 + c] = acc / (1.f + expf(-acc));
    }

#pragma unroll
    for (int k = 1; k <= 8; k++) {
        float m = (t >= k && tk == tr[t - k]) ? 1.f : 0.f;
        o[71 + k] = m;
    }
}

// ---------------------------------------------------------------------------
// Kernel C: scan gates (round-9 exact)
// ---------------------------------------------------------------------------
__global__ __launch_bounds__(256) void k_gates(const float* __restrict__ hf,
                                               const float* __restrict__ gw,
                                               const float* __restrict__ gb,
                                               const float* __restrict__ iw,
                                               const float* __restrict__ ib,
                                               float* __restrict__ Ag,
                                               float* __restrict__ Dr) {
    __shared__ float xs[64][DD];
    __shared__ float gws[32 * 81];
    __shared__ float iws[32 * 81];
    int blk = blockIdx.x;
    int b = blk >> 5;
    int t0 = (blk & 31) << 6;
    const float* src = hf + ((size_t)(b * TT + t0)) * DD;
    for (int i = threadIdx.x; i < 64 * DD; i += 256) xs[i / DD][i % DD] = src[i];
    for (int i = threadIdx.x; i < 32 * 80; i += 256) {
        int s = i / 80, d = i % 80;
        gws[s * 81 + d] = gw[i];
        iws[s * 81 + d] = iw[i];
    }
    __syncthreads();

    for (int p = threadIdx.x; p < 64 * SS; p += 256) {
        int s = p & 31, tt = p >> 5;
        float ga = gb[s], ia = ib[s];
        for (int d = 0; d < DD; d++) {
            float xv = xs[tt][d];
            ga += xv * gws[s * 81 + d];
            ia += xv * iws[s * 81 + d];
        }
        float g = 1.f / (1.f + expf(-ga));
        float drv = (1.f - g) * ia;
        size_t oo = ((size_t)(b * SS + s)) * TT + t0 + tt;
        Ag[oo] = g;
        Dr[oo] = drv;
    }
}

// ---------------------------------------------------------------------------
// Kernel D: parallel chunked scan (round-9 exact)
// ---------------------------------------------------------------------------
__global__ __launch_bounds__(64) void k_scan_par(const float* __restrict__ Ag,
                                                 const float* __restrict__ Dr,
                                                 float* __restrict__ st) {
    int bs = blockIdx.x;
    int b = bs >> 5, s = bs & 31;
    int c = threadIdx.x;
    const float* ar = Ag + (size_t)bs * TT + c * 32;
    const float* dr = Dr + (size_t)bs * TT + c * 32;

    float ca[32], cw[32];
    float lacc = 0.f, wacc = 0.f;
#pragma unroll
    for (int k = 0; k < 32; k += 4) {
        f32x4 av = *(const f32x4*)(ar + k);
        f32x4 dv = *(const f32x4*)(dr + k);
#pragma unroll
        for (int j = 0; j < 4; j++) {
            lacc += logf(fmaxf(av[j], 1e-6f));
            float cav = expf(lacc);
            ca[k + j] = cav;
            wacc += dv[j] / fmaxf(cav, 1e-8f);
            cw[k + j] = wacc;
        }
    }

    float A = ca[31];
    float Bc = ca[31] * wacc;
    for (int off = 1; off < 64; off <<= 1) {
        float Ap = __shfl_up(A, off, 64);
        float Bp = __shfl_up(Bc, off, 64);
        if (c >= off) {
            Bc = A * Bp + Bc;
            A = A * Ap;
        }
    }
    float h0 = __shfl_up(Bc, 1, 64);
    if (c == 0) h0 = 0.f;

    float* op = st + ((size_t)(b * TT + c * 32)) * SS + s;
#pragma unroll
    for (int k = 0; k < 32; k++)
        op[(size_t)k * SS] = ca[k] * (h0 + cw[k]);
}

// ---------------------------------------------------------------------------
// Kernel E: y = st @ outpr_w^T + ob; h1 = LN(hf + y) -> h1p bf16[96] (round-9)
// ---------------------------------------------------------------------------
__global__ __launch_bounds__(256) void k_post(const float* __restrict__ st,
                                              const float* __restrict__ hf,
                                              const float* __restrict__ ow,
                                              const float* __restrict__ ob,
                                              const float* __restrict__ lnw,
                                              const float* __restrict__ lnb,
                                              u16* __restrict__ h1p) {
    __shared__ float ows[DD * SS];
    for (int i = threadIdx.x; i < DD * SS; i += 256) ows[i] = ow[i];
    __syncthreads();

    int idx = blockIdx.x * 256 + threadIdx.x;
    if (idx >= BB * TT) return;
    const float* sp = st + (size_t)idx * SS;
    float sv[SS];
#pragma unroll
    for (int i = 0; i < SS; i += 4) {
        f32x4 v4 = *(const f32x4*)(sp + i);
        sv[i] = v4[0]; sv[i + 1] = v4[1]; sv[i + 2] = v4[2]; sv[i + 3] = v4[3];
    }
    const float* x = hf + (size_t)idx * DD;

    float s1 = 0.f, s2 = 0.f;
    for (int d = 0; d < DD; d++) {
        float acc = ob[d];
#pragma unroll
        for (int i = 0; i < SS; i++) acc += sv[i] * ows[d * SS + i];
        float v = acc + x[d];
        s1 += v; s2 += v * v;
    }
    float m = s1 * (1.f / DD);
    float var = s2 * (1.f / DD) - m * m;
    float rs = rsqrtf(var + 1e-5f);
    u16* o = h1p + (size_t)idx * 96;
    for (int d = 0; d < DD; d++) {
        float acc = ob[d];
#pragma unroll
        for (int i = 0; i < SS; i++) acc += sv[i] * ows[d * SS + i];
        float v = acc + x[d];
        o[d] = f2bu((v - m) * rs * lnw[d] + lnb[d]);
    }
    *(f32x4*)(o + 80) = f32x4{0.f, 0.f, 0.f, 0.f};
    *(f32x4*)(o + 88) = f32x4{0.f, 0.f, 0.f, 0.f};
}

// ---------------------------------------------------------------------------
// Kernel F (fused gmlp, MFMA): per 64-row block:
//   phase1: X = silu(h1p @ inp_w^T + b)      -> LDS Xs (bf16, stride 264)
//   phase2: U = silu(X@w1^T) * (X@w2^T)      -> LDS Us
//   phase3: h3 = LN(U@wp^T + X)              -> global (bf16)
// All MFMA sequences bit-identical to the previous 3 separate kernels;
// X/U merely move through LDS instead of global (same bf16 values).
// Row stride 264 u16 = 528 B: rows walk 4 banks -> <=2-way conflicts (free).
// ---------------------------------------------------------------------------
#define SX 264
__global__ __launch_bounds__(256) void k_gmlp_f(const u16* __restrict__ h1p,
                                                const u16* __restrict__ iwb,
                                                const float* __restrict__ ibias,
                                                const u16* __restrict__ w1,
                                                const u16* __restrict__ w2,
                                                const u16* __restrict__ wp,
                                                const float* __restrict__ lnw,
                                                const float* __restrict__ lnb,
                                                u16* __restrict__ h3) {
    __shared__ u16 Xs[64 * SX];
    __shared__ u16 Us[64 * SX];
    __shared__ float redS[64][4], redQ[64][4];
    int lane = threadIdx.x & 63, wv = threadIdx.x >> 6;
    int r0 = blockIdx.x * 64;
    int g = lane >> 4, cl = lane & 15, rl = lane & 15;

    // ---- phase 1: mlp1 (K=96), wave covers cols [wv*64, +64) ----
    {
        int c0 = wv * 64;
        f32x4 acc[4][4] = {};
#pragma unroll
        for (int ks = 0; ks < 3; ks++) {
            int k0 = ks * 32;
            bf16x8 a[4];
#pragma unroll
            for (int mi = 0; mi < 4; mi++) a[mi] = ldfrag96(h1p, r0 + mi * 16 + rl, k0, lane);
#pragma unroll
            for (int ni = 0; ni < 4; ni++) {
                bf16x8 b = ldfrag96(iwb, c0 + ni * 16 + rl, k0, lane);
#pragma unroll
                for (int mi = 0; mi < 4; mi++) acc[mi][ni] = MFMA(a[mi], b, acc[mi][ni]);
            }
        }
#pragma unroll
        for (int ni = 0; ni < 4; ni++) {
            float bv = ibias[c0 + ni * 16 + cl];
#pragma unroll
            for (int mi = 0; mi < 4; mi++)
#pragma unroll
                for (int r = 0; r < 4; r++) {
                    float v = acc[mi][ni][r] + bv;
                    Xs[(mi * 16 + g * 4 + r) * SX + c0 + ni * 16 + cl] =
                        f2bu(v / (1.f + expf(-v)));
                }
        }
    }
    __syncthreads();

    // ---- phase 2: gemm_u (K=256), wave covers 32 cols x 2 col-groups ----
    for (int cg = 0; cg < 2; cg++) {
        int c0 = cg * 128 + wv * 32;
        f32x4 a1[4][2] = {}, a2[4][2] = {};
        for (int ks = 0; ks < 8; ks++) {
            int k0 = ks * 32 + (g << 3);
            bf16x8 a[4];
#pragma unroll
            for (int mi = 0; mi < 4; mi++)
                a[mi] = *(const bf16x8*)&Xs[(mi * 16 + rl) * SX + k0];
#pragma unroll
            for (int ni = 0; ni < 2; ni++) {
                bf16x8 b1 = ldfrag(w1, c0 + ni * 16 + rl, ks * 32, lane);
                bf16x8 b2 = ldfrag(w2, c0 + ni * 16 + rl, ks * 32, lane);
#pragma unroll
                for (int mi = 0; mi < 4; mi++) {
                    a1[mi][ni] = MFMA(a[mi], b1, a1[mi][ni]);
                    a2[mi][ni] = MFMA(a[mi], b2, a2[mi][ni]);
                }
            }
        }
#pragma unroll
        for (int mi = 0; mi < 4; mi++)
#pragma unroll
            for (int ni = 0; ni < 2; ni++)
#pragma unroll
                for (int r = 0; r < 4; r++) {
                    float v1 = a1[mi][ni][r], v2 = a2[mi][ni][r];
                    float u = v1 / (1.f + expf(-v1)) * v2;
                    Us[(mi * 16 + g * 4 + r) * SX + c0 + ni * 16 + cl] = f2bu(u);
                }
    }
    __syncthreads();

    // ---- phase 3: proj (K=256) + residual + LN -> h3 global ----
    {
        int c0 = wv * 64;
        f32x4 acc[4][4] = {};
        for (int ks = 0; ks < 8; ks++) {
            int k0 = ks * 32 + (g << 3);
            bf16x8 a[4];
#pragma unroll
            for (int mi = 0; mi < 4; mi++)
                a[mi] = *(const bf16x8*)&Us[(mi * 16 + rl) * SX + k0];
#pragma unroll
            for (int ni = 0; ni < 4; ni++) {
                bf16x8 b = ldfrag(wp, c0 + ni * 16 + rl, ks * 32, lane);
#pragma unroll
                for (int mi = 0; mi < 4; mi++) acc[mi][ni] = MFMA(a[mi], b, acc[mi][ni]);
            }
        }
#pragma unroll
        for (int mi = 0; mi < 4; mi++)
#pragma unroll
            for (int r = 0; r < 4; r++) {
                float s = 0.f, q = 0.f;
                int row = mi * 16 + g * 4 + r;
#pragma unroll
                for (int ni = 0; ni < 4; ni++) {
                    int col = c0 + ni * 16 + cl;
                    float v = acc[mi][ni][r] + b2f(Xs[row * SX + col]);
                    acc[mi][ni][r] = v;
                    s += v; q += v * v;
                }
                for (int m = 1; m < 16; m <<= 1) {
                    s += __shfl_xor(s, m, 64);
                    q += __shfl_xor(q, m, 64);
                }
                if (cl == 0) { redS[row][wv] = s; redQ[row][wv] = q; }
            }
        __syncthreads();

        float lw[4], lb[4];
#pragma unroll
        for (int ni = 0; ni < 4; ni++) {
            lw[ni] = lnw[c0 + ni * 16 + cl];
            lb[ni] = lnb[c0 + ni * 16 + cl];
        }
#pragma unroll
        for (int mi = 0; mi < 4; mi++)
#pragma unroll
            for (int r = 0; r < 4; r++) {
                int row = mi * 16 + g * 4 + r;
                float S = redS[row][0] + redS[row][1] + redS[row][2] + redS[row][3];
                float Q = redQ[row][0] + redQ[row][1] + redQ[row][2] + redQ[row][3];
                float m = S * (1.f / 256.f);
                float rs = rsqrtf(Q * (1.f / 256.f) - m * m + 1e-5f);
#pragma unroll
                for (int ni = 0; ni < 4; ni++) {
                    float y = (acc[mi][ni][r] - m) * rs * lw[ni] + lb[ni];
                    h3[(size_t)(r0 + row) * 256 + c0 + ni * 16 + cl] = f2bu(y);
                }
            }
    }
}

// ---------------------------------------------------------------------------
// Kernel H (MFMA): out = h3 @ out_w^T + out_b. 128-row tile, col-group loop
// inside (A re-staged from hot L2 instead of 8x from HBM). BK=32 dbuf LDS.
// ---------------------------------------------------------------------------
#define SA 40
__global__ __launch_bounds__(256) void k_out4(const u16* __restrict__ h3,
                                              const u16* __restrict__ ow,
                                              const float* __restrict__ bias,
                                              float* __restrict__ out) {
    __shared__ u16 As[2][128 * SA];
    __shared__ u16 Bs[2][128 * SA];
    int tid = threadIdx.x, lane = tid & 63, wv = tid >> 6;
    int r0 = blockIdx.x * 128;
    int wr = (wv >> 1) * 64, wc = (wv & 1) * 64;
    int rl = lane & 15, g = lane >> 4;

    int row0_ = tid >> 2, cc0_ = tid & 3;
    int row1_ = (tid + 256) >> 2, cc1_ = tid & 3;
    bf16x8 rA0, rA1, rB0, rB1;

#define LOADT(cg, kt)                                                                      \
    {                                                                                      \
        int kbase = (kt) * 32;                                                             \
        int c0g = (cg) * 128;                                                              \
        rA0 = *(const bf16x8*)(h3 + (size_t)(r0 + row0_) * 256 + kbase + cc0_ * 8);        \
        rA1 = *(const bf16x8*)(h3 + (size_t)(r0 + row1_) * 256 + kbase + cc1_ * 8);        \
        rB0 = *(const bf16x8*)(ow + (size_t)(c0g + row0_) * 256 + kbase + cc0_ * 8);       \
        rB1 = *(const bf16x8*)(ow + (size_t)(c0g + row1_) * 256 + kbase + cc1_ * 8);       \
    }
#define WRITET(buf)                                                                        \
    {                                                                                      \
        *(bf16x8*)&As[buf][row0_ * SA + cc0_ * 8] = rA0;                                   \
        *(bf16x8*)&As[buf][row1_ * SA + cc1_ * 8] = rA1;                                   \
        *(bf16x8*)&Bs[buf][row0_ * SA + cc0_ * 8] = rB0;                                   \
        *(bf16x8*)&Bs[buf][row1_ * SA + cc1_ * 8] = rB1;                                   \
    }

    for (int cg = 0; cg < 8; cg++) {
        // All waves have passed the kt=7 barrier of the previous cg, whose
        // compute used buffer 1 only -> writing buffer 0 here is race-free.
        LOADT(cg, 0);
        WRITET(0);
        f32x4 acc[4][4] = {};
        for (int kt = 0; kt < 8; kt++) {
            int buf = kt & 1;
            if (kt < 7) LOADT(cg, kt + 1);
            __syncthreads();
            bf16x8 a[4], b[4];
#pragma unroll
            for (int mi = 0; mi < 4; mi++)
                a[mi] = *(const bf16x8*)&As[buf][(wr + mi * 16 + rl) * SA + g * 8];
#pragma unroll
            for (int ni = 0; ni < 4; ni++)
                b[ni] = *(const bf16x8*)&Bs[buf][(wc + ni * 16 + rl) * SA + g * 8];
#pragma unroll
            for (int ni = 0; ni < 4; ni++)
#pragma unroll
                for (int mi = 0; mi < 4; mi++) acc[mi][ni] = MFMA(a[mi], b[ni], acc[mi][ni]);
            if (kt < 7) WRITET(buf ^ 1);
        }
        int c0g = cg * 128;
        int cl = lane & 15;
#pragma unroll
        for (int ni = 0; ni < 4; ni++) {
            float bv = bias[c0g + wc + ni * 16 + cl];
#pragma unroll
            for (int mi = 0; mi < 4; mi++)
#pragma unroll
                for (int r = 0; r < 4; r++)
                    out[(size_t)(r0 + wr + mi * 16 + g * 4 + r) * VV + c0g + wc + ni * 16 + cl] =
                        acc[mi][ni][r] + bv;
        }
        __syncthreads();   // acc written out; safe for next cg's WRITET(0)
    }
#undef LOADT
#undef WRITET
}

// ---------------------------------------------------------------------------
extern "C" void kernel_launch(void* const* d_in, const int* in_sizes, int n_in,
                              void* d_out, int out_size, void* d_ws, size_t ws_size,
                              hipStream_t stream) {
    const int* chars        = (const int*)d_in[0];
    const float* byte_embed = (const float*)d_in[1];
    const float* table0     = (const float*)d_in[2];
    const float* table1     = (const float*)d_in[3];
    const float* table2     = (const float*)d_in[4];
    const float* table3     = (const float*)d_in[5];
    const float* cond_w     = (const float*)d_in[6];
    const float* conv_w     = (const float*)d_in[7];
    const float* conv_b     = (const float*)d_in[8];
    const float* gate_w     = (const float*)d_in[9];
    const float* gate_b     = (const float*)d_in[10];
    const float* inpr_w     = (const float*)d_in[11];
    const float* inpr_b     = (const float*)d_in[12];
    const float* outpr_w    = (const float*)d_in[13];
    const float* outpr_b    = (const float*)d_in[14];
    const float* scan_ln_w  = (const float*)d_in[15];
    const float* scan_ln_b  = (const float*)d_in[16];
    const float* inp_w      = (const float*)d_in[17];
    const float* inp_b      = (const float*)d_in[18];
    const float* r_w1       = (const float*)d_in[19];
    const float* r_w2       = (const float*)d_in[20];
    const float* r_proj     = (const float*)d_in[21];
    const float* r_ln_w     = (const float*)d_in[22];
    const float* r_ln_b     = (const float*)d_in[23];
    const float* out_w      = (const float*)d_in[24];
    const float* out_b      = (const float*)d_in[25];

    // ws layout with lifetimes (peak 61.9 MB):
    //   wbf  [0, 0.97M)       prep..end
    //   hf   [1M, 24.1M)      feat..post (f32, stride 80)
    //   raw  [24.1M, 26.2M)   hash..feat
    //   Ag   [24.1M, 32.5M)   gates..scan (over raw after feat)
    //   Dr   [32.5M, 40.9M)   gates..scan
    //   st   [40.9M, 49.3M)   scan..post
    //   h1p  [49.3M, 61.9M)   post..gmlp_f (bf16, stride 96)
    //   h3b  [1M, 34.6M)      gmlp_f..out4 (over hf/Ag/Dr-head: all dead;
    //                          disjoint from h1p which gmlp_f still reads)
    char* ws = (char*)d_ws;
    u16*   wbf = (u16*)(ws + 0);
    u16*   w1b = wbf;
    u16*   w2b = wbf + 65536;
    u16*   wpb = wbf + 131072;
    u16*   owb = wbf + 196608;
    u16*   iwb = wbf + 458752;
    float* hf  = (float*)(ws + 1048576);
    float* raw = (float*)(ws + 24117248);
    float* Ag  = (float*)(ws + 24117248);
    float* Dr  = (float*)(ws + 32505856);
    float* st  = (float*)(ws + 40894464);
    u16*   h1p = (u16*)(ws + 49283072);
    u16*   h3b = (u16*)(ws + 1048576);
    float* out = (float*)d_out;

    k_prep <<<1888, 256, 0, stream>>>(r_w1, r_w2, r_proj, out_w, inp_w, wbf);
    k_hash <<<256, 256, 0, stream>>>(chars, table0, table1, table2, table3, cond_w, raw);
    k_feat <<<256, 256, 0, stream>>>(chars, byte_embed, raw, conv_w, conv_b, hf);
    k_gates<<<1024, 256, 0, stream>>>(hf, gate_w, gate_b, inpr_w, inpr_b, Ag, Dr);
    k_scan_par<<<1024, 64, 0, stream>>>(Ag, Dr, st);
    k_post <<<256, 256, 0, stream>>>(st, hf, outpr_w, outpr_b, scan_ln_w, scan_ln_b, h1p);
    k_gmlp_f<<<1024, 256, 0, stream>>>(h1p, iwb, inp_b, w1b, w2b, wpb, r_ln_w, r_ln_b, h3b);
    k_out4 <<<512, 256, 0, stream>>>(h3b, owb, out_b, out);
}